// Round 15
// baseline (143.128 us; speedup 1.0000x reference)
//
#include <hip/hip_runtime.h>
#include <hip/hip_bf16.h>
#include <math.h>

#define NN 1024
#define CC 128
#define C2 64
#define KK 16
#define NCAND 24

#if __has_builtin(__builtin_amdgcn_exp2f)
#define EXP2F(x) __builtin_amdgcn_exp2f(x)
#else
#define EXP2F(x) exp2f(x)
#endif
#define LOG2E 1.4426950408889634f

typedef short short8 __attribute__((ext_vector_type(8)));
typedef float f32x4  __attribute__((ext_vector_type(4)));
typedef int   int4v  __attribute__((ext_vector_type(4)));
typedef unsigned int uint;

__device__ __forceinline__ float fast_rcp(float x) {
    return __builtin_amdgcn_rcpf(x);
}
__device__ __forceinline__ unsigned short f2bf(float x) {   // RNE f32->bf16
    unsigned int u = __float_as_uint(x);
    unsigned int r = (u + 0x7FFFu + ((u >> 16) & 1u)) >> 16;
    return (unsigned short)r;
}
__device__ __forceinline__ float bf2f(unsigned short h) {
    return __uint_as_float(((unsigned int)h) << 16);
}

// In-wave LDS write->read visibility: wait LDS ops, pin compiler order.
#define LDS_FENCE() do { \
    asm volatile("s_waitcnt lgkmcnt(0)" ::: "memory"); \
    __builtin_amdgcn_sched_barrier(0); } while (0)

// ---------------- K0: A = M^T M, f32, ascending-r fmaf chain (np-exact) ----
__global__ __launch_bounds__(256) void buildA(const float* __restrict__ M,
                                              float* __restrict__ A) {
    const int e = blockIdx.x * 256 + threadIdx.x;    // 4096 entries
    const int c = e >> 6, d = e & 63;
    float acc = 0.f;
    #pragma unroll 8
    for (int r = 0; r < C2; ++r)
        acc = fmaf(M[r * C2 + c], M[r * C2 + d], acc);
    A[e] = acc;                                      // A[c][d] row-major
}

// ---------------- K1: projections + logmap, f32 (np-exact) + psE -----------
__global__ __launch_bounds__(128) void proj(
        const float* __restrict__ X,
        const float* __restrict__ Wm,
        const float* __restrict__ Ws,
        float* __restrict__ pm,
        float* __restrict__ ps,
        float* __restrict__ psE) {
    const int bn = blockIdx.x;           // b*1024 + n
    const int b  = bn >> 10;
    const int n  = bn & (NN - 1);
    const int t  = threadIdx.x;          // 0..127

    __shared__ float xv[CC];
    xv[t] = X[b * CC * NN + t * NN + n];
    __syncthreads();

    const int d = t & (C2 - 1);
    const float* wr = ((t < C2) ? Wm : Ws) + d * CC;
    float acc = 0.f;
    #pragma unroll
    for (int c = 0; c < CC; ++c)
        acc = fmaf(wr[c], xv[c], acc);   // sequential k-order, single acc

    float a = __fadd_rn(fabsf(acc), 1e-10f);
    float l = logf(a);
    float r = (acc > 0.f) ? l : ((acc < 0.f) ? -l : 0.f);
    if (t < C2) {
        pm[bn * C2 + d] = r;
    } else {
        ps[bn * C2 + d] = r;
        psE[bn * C2 + d] = EXP2F(r * LOG2E);   // e^ps (proxy pass only)
    }
}

// Build bhi/blo bf16 fragments from 8 sigmoids (truncation split; proxy only)
#define SIG_PACK(Y0, Y1, KT, BHI, BLO) do {                                   \
    float s0 = pmEf[KT][0] * fast_rcp(pmEf[KT][0] + (Y0).x);                  \
    float s1 = pmEf[KT][1] * fast_rcp(pmEf[KT][1] + (Y0).y);                  \
    float s2 = pmEf[KT][2] * fast_rcp(pmEf[KT][2] + (Y0).z);                  \
    float s3 = pmEf[KT][3] * fast_rcp(pmEf[KT][3] + (Y0).w);                  \
    float s4 = pmEf[KT][4] * fast_rcp(pmEf[KT][4] + (Y1).x);                  \
    float s5 = pmEf[KT][5] * fast_rcp(pmEf[KT][5] + (Y1).y);                  \
    float s6 = pmEf[KT][6] * fast_rcp(pmEf[KT][6] + (Y1).z);                  \
    float s7 = pmEf[KT][7] * fast_rcp(pmEf[KT][7] + (Y1).w);                  \
    uint u0 = __float_as_uint(s0), u1 = __float_as_uint(s1);                  \
    uint u2 = __float_as_uint(s2), u3 = __float_as_uint(s3);                  \
    uint u4 = __float_as_uint(s4), u5 = __float_as_uint(s5);                  \
    uint u6 = __float_as_uint(s6), u7 = __float_as_uint(s7);                  \
    uint l0 = __float_as_uint(s0 - __uint_as_float(u0 & 0xFFFF0000u));        \
    uint l1 = __float_as_uint(s1 - __uint_as_float(u1 & 0xFFFF0000u));        \
    uint l2 = __float_as_uint(s2 - __uint_as_float(u2 & 0xFFFF0000u));        \
    uint l3 = __float_as_uint(s3 - __uint_as_float(u3 & 0xFFFF0000u));        \
    uint l4 = __float_as_uint(s4 - __uint_as_float(u4 & 0xFFFF0000u));        \
    uint l5 = __float_as_uint(s5 - __uint_as_float(u5 & 0xFFFF0000u));        \
    uint l6 = __float_as_uint(s6 - __uint_as_float(u6 & 0xFFFF0000u));        \
    uint l7 = __float_as_uint(s7 - __uint_as_float(u7 & 0xFFFF0000u));        \
    int4v hiv = { (int)__builtin_amdgcn_perm(u1, u0, 0x07060302u),            \
                  (int)__builtin_amdgcn_perm(u3, u2, 0x07060302u),            \
                  (int)__builtin_amdgcn_perm(u5, u4, 0x07060302u),            \
                  (int)__builtin_amdgcn_perm(u7, u6, 0x07060302u) };          \
    int4v lov = { (int)__builtin_amdgcn_perm(l1, l0, 0x07060302u),            \
                  (int)__builtin_amdgcn_perm(l3, l2, 0x07060302u),            \
                  (int)__builtin_amdgcn_perm(l5, l4, 0x07060302u),            \
                  (int)__builtin_amdgcn_perm(l7, l6, 0x07060302u) };          \
    BHI = __builtin_bit_cast(short8, hiv);                                    \
    BLO = __builtin_bit_cast(short8, lov);                                    \
} while (0)

#define MFMA12(AC, KT, BHI, BLO)                                                        \
    AC[0] = __builtin_amdgcn_mfma_f32_16x16x32_bf16(ahi[0][KT], BHI, AC[0], 0, 0, 0);   \
    AC[0] = __builtin_amdgcn_mfma_f32_16x16x32_bf16(ahi[0][KT], BLO, AC[0], 0, 0, 0);   \
    AC[0] = __builtin_amdgcn_mfma_f32_16x16x32_bf16(alo[0][KT], BHI, AC[0], 0, 0, 0);   \
    AC[1] = __builtin_amdgcn_mfma_f32_16x16x32_bf16(ahi[1][KT], BHI, AC[1], 0, 0, 0);   \
    AC[1] = __builtin_amdgcn_mfma_f32_16x16x32_bf16(ahi[1][KT], BLO, AC[1], 0, 0, 0);   \
    AC[1] = __builtin_amdgcn_mfma_f32_16x16x32_bf16(alo[1][KT], BHI, AC[1], 0, 0, 0);   \
    AC[2] = __builtin_amdgcn_mfma_f32_16x16x32_bf16(ahi[2][KT], BHI, AC[2], 0, 0, 0);   \
    AC[2] = __builtin_amdgcn_mfma_f32_16x16x32_bf16(ahi[2][KT], BLO, AC[2], 0, 0, 0);   \
    AC[2] = __builtin_amdgcn_mfma_f32_16x16x32_bf16(alo[2][KT], BHI, AC[2], 0, 0, 0);   \
    AC[3] = __builtin_amdgcn_mfma_f32_16x16x32_bf16(ahi[3][KT], BHI, AC[3], 0, 0, 0);   \
    AC[3] = __builtin_amdgcn_mfma_f32_16x16x32_bf16(ahi[3][KT], BLO, AC[3], 0, 0, 0);   \
    AC[3] = __builtin_amdgcn_mfma_f32_16x16x32_bf16(alo[3][KT], BHI, AC[3], 0, 0, 0);

// ---------------- K2: 2 waves per row, 1024 blocks x 256 thr (4 waves) -----
// Wave = (row_local rl = wv>>1, j-half = wv&1). 4096 waves total = 4/SIMD.
//  A: proxy dis2, 3-term-split MFMA; wave does 32 j-tiles (its half)
//  B: both waves of a pair run top-24 redundantly (same d2u -> same result)
//  C: wave rescores candidates [half*12, +12) with R6's EXACT np-f32 op order
//  F: half==0 wave does top-16 merge (desc diff, asc index) -> out
__global__ __launch_bounds__(256, 2) void pair_topk(
        const float* __restrict__ pm,
        const float* __restrict__ ps,
        const float* __restrict__ psE,
        const float* __restrict__ Mf,
        const float* __restrict__ A,
        float* __restrict__ out) {
    const int tid  = threadIdx.x;
    const int wv   = tid >> 6;           // 0..3
    const int lane = tid & 63;
    const int g    = lane >> 4;          // k-group 0..3
    const int lj   = lane & 15;          // col (B) / row (A) within tile
    const int rl   = wv >> 1;            // row_local 0..1
    const int half = wv & 1;             // j-half 0..1

    const int bi = blockIdx.x * 2 + rl;  // row 0..2047
    const int b  = bi >> 10;
    const int i  = bi & (NN - 1);

    __shared__ uint  d2u[2][NN];         // packed (d2 & ~0x3FF) | j  (8 KB)
    __shared__ float sC[4][C2];
    __shared__ float cdiffL[2][NCAND];

    const float* psb  = ps  + b * NN * C2;
    const float* psEb = psE + b * NN * C2;

    const float pm_own = pm[bi * C2 + lane];         // exact (phase C)

    float pmEf[2][8];
    #pragma unroll
    for (int kt = 0; kt < 2; ++kt) {
        const float4 a0 = *(const float4*)(pm + bi * C2 + kt * 32 + g * 8);
        const float4 a1 = *(const float4*)(pm + bi * C2 + kt * 32 + g * 8 + 4);
        pmEf[kt][0] = EXP2F(a0.x * LOG2E); pmEf[kt][1] = EXP2F(a0.y * LOG2E);
        pmEf[kt][2] = EXP2F(a0.z * LOG2E); pmEf[kt][3] = EXP2F(a0.w * LOG2E);
        pmEf[kt][4] = EXP2F(a1.x * LOG2E); pmEf[kt][5] = EXP2F(a1.y * LOG2E);
        pmEf[kt][6] = EXP2F(a1.z * LOG2E); pmEf[kt][7] = EXP2F(a1.w * LOG2E);
    }

    // ---- Phase A: 32 tiles = 16 iters x 2 tiles (this wave's j-half) ----
    {
        short8 ahi[4][2], alo[4][2];     // M rows hi/lo bf16 (RNE, once)
        #pragma unroll
        for (int rt = 0; rt < 4; ++rt) {
            #pragma unroll
            for (int kt = 0; kt < 2; ++kt) {
                const float* mrow = Mf + (rt * 16 + lj) * C2 + kt * 32 + g * 8;
                const float4 m0 = *(const float4*)mrow;
                const float4 m1 = *(const float4*)(mrow + 4);
                float mv[8] = {m0.x, m0.y, m0.z, m0.w, m1.x, m1.y, m1.z, m1.w};
                #pragma unroll
                for (int e = 0; e < 8; ++e) {
                    unsigned short h = f2bf(mv[e]);
                    ahi[rt][kt][e] = (short)h;
                    alo[rt][kt][e] = (short)f2bf(mv[e] - bf2f(h));
                }
            }
        }

        const int tbase = half * 32;     // first tile of this wave's half
        const float* p0 = psEb + (long)((tbase + 0) * 16 + lj) * C2 + g * 8;
        const float* p1 = psEb + (long)((tbase + 1) * 16 + lj) * C2 + g * 8;
        float4 cA0 = *(const float4*)(p0);      float4 cA1 = *(const float4*)(p0 + 4);
        float4 cA2 = *(const float4*)(p0 + 32); float4 cA3 = *(const float4*)(p0 + 36);
        float4 cB0 = *(const float4*)(p1);      float4 cB1 = *(const float4*)(p1 + 4);
        float4 cB2 = *(const float4*)(p1 + 32); float4 cB3 = *(const float4*)(p1 + 36);

        #pragma unroll 1
        for (int it = 0; it < 16; ++it) {
            float4 nA0, nA1, nA2, nA3, nB0, nB1, nB2, nB3;
            if (it < 15) {                       // issue next-iter loads EARLY
                const float* q0 = psEb + (long)((tbase + it * 2 + 2) * 16 + lj) * C2 + g * 8;
                const float* q1 = psEb + (long)((tbase + it * 2 + 3) * 16 + lj) * C2 + g * 8;
                nA0 = *(const float4*)(q0);      nA1 = *(const float4*)(q0 + 4);
                nA2 = *(const float4*)(q0 + 32); nA3 = *(const float4*)(q0 + 36);
                nB0 = *(const float4*)(q1);      nB1 = *(const float4*)(q1 + 4);
                nB2 = *(const float4*)(q1 + 32); nB3 = *(const float4*)(q1 + 36);
            }

            short8 hA0, lA0, hA1, lA1, hB0, lB0, hB1, lB1;
            SIG_PACK(cA0, cA1, 0, hA0, lA0);
            SIG_PACK(cA2, cA3, 1, hA1, lA1);
            SIG_PACK(cB0, cB1, 0, hB0, lB0);
            SIG_PACK(cB2, cB3, 1, hB1, lB1);

            f32x4 accA[4] = {{0,0,0,0},{0,0,0,0},{0,0,0,0},{0,0,0,0}};
            f32x4 accB[4] = {{0,0,0,0},{0,0,0,0},{0,0,0,0},{0,0,0,0}};

            __builtin_amdgcn_s_setprio(1);
            MFMA12(accA, 0, hA0, lA0)
            MFMA12(accB, 0, hB0, lB0)
            MFMA12(accA, 1, hA1, lA1)
            MFMA12(accB, 1, hB1, lB1)
            __builtin_amdgcn_s_setprio(0);

            float sqA = 0.f, sqB = 0.f;
            #pragma unroll
            for (int e = 0; e < 4; ++e) {
                sqA = fmaf(accA[0][e], accA[0][e], sqA);
                sqA = fmaf(accA[1][e], accA[1][e], sqA);
                sqA = fmaf(accA[2][e], accA[2][e], sqA);
                sqA = fmaf(accA[3][e], accA[3][e], sqA);
                sqB = fmaf(accB[0][e], accB[0][e], sqB);
                sqB = fmaf(accB[1][e], accB[1][e], sqB);
                sqB = fmaf(accB[2][e], accB[2][e], sqB);
                sqB = fmaf(accB[3][e], accB[3][e], sqB);
            }
            sqA += __shfl_xor(sqA, 16, 64);
            sqA += __shfl_xor(sqA, 32, 64);
            sqB += __shfl_xor(sqB, 16, 64);
            sqB += __shfl_xor(sqB, 32, 64);
            if (lane < 16) {
                const int jA = (tbase + it * 2 + 0) * 16 + lane;
                const int jB = (tbase + it * 2 + 1) * 16 + lane;
                d2u[rl][jA] = (__float_as_uint(sqA) & 0xFFFFFC00u) | (uint)jA;
                d2u[rl][jB] = (__float_as_uint(sqB) & 0xFFFFFC00u) | (uint)jB;
            }

            cA0 = nA0; cA1 = nA1; cA2 = nA2; cA3 = nA3;
            cB0 = nB0; cB1 = nB1; cB2 = nB2; cB3 = nB3;
        }
    }
    __syncthreads();

    // ---- Phase B: top-24 via packed-uint min passes (both waves of pair,
    //      redundant but parallel; identical inputs -> identical results) ----
    uint v[16];
    #pragma unroll
    for (int q = 0; q < 16; ++q) v[q] = d2u[rl][q * 64 + lane];

    int myCand = 0;
    #pragma unroll 1
    for (int k = 0; k < NCAND; ++k) {
        uint bv = v[0];
        #pragma unroll
        for (int q = 1; q < 16; ++q) bv = min(bv, v[q]);
        #pragma unroll
        for (int st = 0; st < 6; ++st)
            bv = min(bv, (uint)__shfl_xor((int)bv, 1 << st, 64));
        #pragma unroll
        for (int q = 0; q < 16; ++q)
            if (v[q] == bv) v[q] = 0xFFFFFFFFu;
        if (lane == k) myCand = (int)(bv & 0x3FFu);
    }

    // ---- Phase C: np-exact rescore (R6 bit-exact); 12 candidates/wave ----
    float Acol[C2];
    #pragma unroll
    for (int c = 0; c < C2; ++c) Acol[c] = A[c * C2 + lane];

    // prefetch all 12 candidate ps values (batch issue, one wait)
    int jv[12];
    #pragma unroll
    for (int t = 0; t < 12; ++t) jv[t] = __shfl(myCand, half * 12 + t, 64);
    float pscv[12];
    #pragma unroll
    for (int t = 0; t < 12; ++t) pscv[t] = psb[(long)jv[t] * C2 + lane];

    #pragma unroll
    for (int t = 0; t < 12; ++t) {
        const int tc = half * 12 + t;
        float e = expf(pscv[t] - pm_own);
        float s_own = 1.0f / __fadd_rn(1.0f, e);     // sigmoid(pm-ps), lane=c
        sC[wv][lane] = s_own;
        LDS_FENCE();
        float wd = 0.f;
        #pragma unroll
        for (int c = 0; c < C2; ++c)                 // ascending c, single acc
            wd = fmaf(sC[wv][c], Acol[c], wd);
        const float t_own = __fmul_rn(wd, s_own);    // t_d = w_d * s_d, lane=d
        // numpy pairwise-8 via shfl (same op order as np)
        float r8 = t_own;
        #pragma unroll
        for (int blk = 1; blk < 8; ++blk)
            r8 = __fadd_rn(r8, __shfl(t_own, (lane & 7) + 8 * blk, 64));
        const float rr0 = __shfl(r8, 0, 64), rr1 = __shfl(r8, 1, 64);
        const float rr2 = __shfl(r8, 2, 64), rr3 = __shfl(r8, 3, 64);
        const float rr4 = __shfl(r8, 4, 64), rr5 = __shfl(r8, 5, 64);
        const float rr6 = __shfl(r8, 6, 64), rr7 = __shfl(r8, 7, 64);
        float dis2 = __fadd_rn(
            __fadd_rn(__fadd_rn(rr0, rr1), __fadd_rn(rr2, rr3)),
            __fadd_rn(__fadd_rn(rr4, rr5), __fadd_rn(rr6, rr7)));
        float disf = sqrtf(dis2);
        float ee = expf(disf);
        float cd = 1.0f / __fadd_rn(1.0f, ee);       // sigmoid(-dis)
        if (lane == 0) cdiffL[rl][tc] = cd;
    }
    __syncthreads();

    // ---- Final: half==0 wave: top-16 over 24 exact diffs (desc, asc idx) ----
    if (half == 0) {
        float myd = (lane < NCAND) ? cdiffL[rl][lane] : -2.0f;
        int myj = (lane < NCAND) ? myCand : (1 << 20);

        const int obase = b * (NN * KK) + i * KK;    // index chunk (f32)
        const int vbase = 2 * NN * KK + obase;       // value chunk (f32)

        #pragma unroll 1
        for (int k = 0; k < KK; ++k) {
            float bd = myd;
            int bj = myj;
            #pragma unroll
            for (int st = 0; st < 6; ++st) {
                int msk = 1 << st;
                float od = __shfl_xor(bd, msk, 64);
                int oj = __shfl_xor(bj, msk, 64);
                bool better = (od > bd) || (od == bd && oj < bj);
                bd = better ? od : bd;
                bj = better ? oj : bj;
            }
            if (myj == bj) myd = -2.0f;              // candidate j's unique
            if (lane == 0) {
                out[obase + k] = (float)bj;
                out[vbase + k] = -bd;                // value = -topk(diff)
            }
        }
    }
}

extern "C" void kernel_launch(void* const* d_in, const int* in_sizes, int n_in,
                              void* d_out, int out_size, void* d_ws, size_t ws_size,
                              hipStream_t stream) {
    const float* X  = (const float*)d_in[0];
    const float* Wm = (const float*)d_in[1];
    const float* Ws = (const float*)d_in[2];
    const float* M  = (const float*)d_in[3];

    float* A   = (float*)d_ws;           // 4096 f   (16 KB)
    float* pm  = A + C2 * C2;            // 131072 f (512 KB)
    float* ps  = pm + 2 * NN * C2;       // 131072 f (512 KB)
    float* psE = ps + 2 * NN * C2;       // 131072 f (512 KB)  total ~1.52 MB
    float* out = (float*)d_out;          // f32: [idx 32768][val 32768]

    hipLaunchKernelGGL(buildA, dim3(16), dim3(256), 0, stream, M, A);
    hipLaunchKernelGGL(proj, dim3(2 * NN), dim3(128), 0, stream,
                       X, Wm, Ws, pm, ps, psE);
    hipLaunchKernelGGL(pair_topk, dim3(NN), dim3(256), 0, stream,
                       pm, ps, psE, M, A, out);
}

// Round 16
// 117.281 us; speedup vs baseline: 1.2204x; 1.2204x over previous
//
#include <hip/hip_runtime.h>
#include <hip/hip_bf16.h>
#include <math.h>

#define NN 1024
#define CC 128
#define C2 64
#define KK 16
#define NCAND 24

#if __has_builtin(__builtin_amdgcn_exp2f)
#define EXP2F(x) __builtin_amdgcn_exp2f(x)
#else
#define EXP2F(x) exp2f(x)
#endif
#define LOG2E 1.4426950408889634f

typedef short short8 __attribute__((ext_vector_type(8)));
typedef float f32x4  __attribute__((ext_vector_type(4)));
typedef int   int4v  __attribute__((ext_vector_type(4)));
typedef unsigned int uint;

__device__ __forceinline__ float fast_rcp(float x) {
    return __builtin_amdgcn_rcpf(x);
}
__device__ __forceinline__ unsigned short f2bf(float x) {   // RNE f32->bf16
    unsigned int u = __float_as_uint(x);
    unsigned int r = (u + 0x7FFFu + ((u >> 16) & 1u)) >> 16;
    return (unsigned short)r;
}
__device__ __forceinline__ float bf2f(unsigned short h) {
    return __uint_as_float(((unsigned int)h) << 16);
}

// In-wave LDS write->read visibility: wait LDS ops, pin compiler order.
#define LDS_FENCE() do { \
    asm volatile("s_waitcnt lgkmcnt(0)" ::: "memory"); \
    __builtin_amdgcn_sched_barrier(0); } while (0)

// ---------------- K0: A = M^T M, f32, ascending-r fmaf chain (np-exact) ----
__global__ __launch_bounds__(256) void buildA(const float* __restrict__ M,
                                              float* __restrict__ A) {
    const int e = blockIdx.x * 256 + threadIdx.x;    // 4096 entries
    const int c = e >> 6, d = e & 63;
    float acc = 0.f;
    #pragma unroll 8
    for (int r = 0; r < C2; ++r)
        acc = fmaf(M[r * C2 + c], M[r * C2 + d], acc);
    A[e] = acc;                                      // A[c][d] row-major
}

// ---------------- K1: projections + logmap, f32 (np-exact) + psE -----------
__global__ __launch_bounds__(128) void proj(
        const float* __restrict__ X,
        const float* __restrict__ Wm,
        const float* __restrict__ Ws,
        float* __restrict__ pm,
        float* __restrict__ ps,
        float* __restrict__ psE) {
    const int bn = blockIdx.x;           // b*1024 + n
    const int b  = bn >> 10;
    const int n  = bn & (NN - 1);
    const int t  = threadIdx.x;          // 0..127

    __shared__ float xv[CC];
    xv[t] = X[b * CC * NN + t * NN + n];
    __syncthreads();

    const int d = t & (C2 - 1);
    const float* wr = ((t < C2) ? Wm : Ws) + d * CC;
    float acc = 0.f;
    #pragma unroll
    for (int c = 0; c < CC; ++c)
        acc = fmaf(wr[c], xv[c], acc);   // sequential k-order, single acc

    float a = __fadd_rn(fabsf(acc), 1e-10f);
    float l = logf(a);
    float r = (acc > 0.f) ? l : ((acc < 0.f) ? -l : 0.f);
    if (t < C2) {
        pm[bn * C2 + d] = r;
    } else {
        ps[bn * C2 + d] = r;
        psE[bn * C2 + d] = EXP2F(r * LOG2E);   // e^ps (proxy pass only)
    }
}

// Build bhi/blo bf16 fragments from 8 sigmoids (truncation split; proxy only)
// PMEF: name of the row's pmEf[2][8] array.
#define SIG_PACK(PMEF, Y0, Y1, KT, BHI, BLO) do {                             \
    float s0 = PMEF[KT][0] * fast_rcp(PMEF[KT][0] + (Y0).x);                  \
    float s1 = PMEF[KT][1] * fast_rcp(PMEF[KT][1] + (Y0).y);                  \
    float s2 = PMEF[KT][2] * fast_rcp(PMEF[KT][2] + (Y0).z);                  \
    float s3 = PMEF[KT][3] * fast_rcp(PMEF[KT][3] + (Y0).w);                  \
    float s4 = PMEF[KT][4] * fast_rcp(PMEF[KT][4] + (Y1).x);                  \
    float s5 = PMEF[KT][5] * fast_rcp(PMEF[KT][5] + (Y1).y);                  \
    float s6 = PMEF[KT][6] * fast_rcp(PMEF[KT][6] + (Y1).z);                  \
    float s7 = PMEF[KT][7] * fast_rcp(PMEF[KT][7] + (Y1).w);                  \
    uint u0 = __float_as_uint(s0), u1 = __float_as_uint(s1);                  \
    uint u2 = __float_as_uint(s2), u3 = __float_as_uint(s3);                  \
    uint u4 = __float_as_uint(s4), u5 = __float_as_uint(s5);                  \
    uint u6 = __float_as_uint(s6), u7 = __float_as_uint(s7);                  \
    uint l0 = __float_as_uint(s0 - __uint_as_float(u0 & 0xFFFF0000u));        \
    uint l1 = __float_as_uint(s1 - __uint_as_float(u1 & 0xFFFF0000u));        \
    uint l2 = __float_as_uint(s2 - __uint_as_float(u2 & 0xFFFF0000u));        \
    uint l3 = __float_as_uint(s3 - __uint_as_float(u3 & 0xFFFF0000u));        \
    uint l4 = __float_as_uint(s4 - __uint_as_float(u4 & 0xFFFF0000u));        \
    uint l5 = __float_as_uint(s5 - __uint_as_float(u5 & 0xFFFF0000u));        \
    uint l6 = __float_as_uint(s6 - __uint_as_float(u6 & 0xFFFF0000u));        \
    uint l7 = __float_as_uint(s7 - __uint_as_float(u7 & 0xFFFF0000u));        \
    int4v hiv = { (int)__builtin_amdgcn_perm(u1, u0, 0x07060302u),            \
                  (int)__builtin_amdgcn_perm(u3, u2, 0x07060302u),            \
                  (int)__builtin_amdgcn_perm(u5, u4, 0x07060302u),            \
                  (int)__builtin_amdgcn_perm(u7, u6, 0x07060302u) };          \
    int4v lov = { (int)__builtin_amdgcn_perm(l1, l0, 0x07060302u),            \
                  (int)__builtin_amdgcn_perm(l3, l2, 0x07060302u),            \
                  (int)__builtin_amdgcn_perm(l5, l4, 0x07060302u),            \
                  (int)__builtin_amdgcn_perm(l7, l6, 0x07060302u) };          \
    BHI = __builtin_bit_cast(short8, hiv);                                    \
    BLO = __builtin_bit_cast(short8, lov);                                    \
} while (0)

#define MFMA12(AC, KT, BHI, BLO)                                                        \
    AC[0] = __builtin_amdgcn_mfma_f32_16x16x32_bf16(ahi[0][KT], BHI, AC[0], 0, 0, 0);   \
    AC[0] = __builtin_amdgcn_mfma_f32_16x16x32_bf16(ahi[0][KT], BLO, AC[0], 0, 0, 0);   \
    AC[0] = __builtin_amdgcn_mfma_f32_16x16x32_bf16(alo[0][KT], BHI, AC[0], 0, 0, 0);   \
    AC[1] = __builtin_amdgcn_mfma_f32_16x16x32_bf16(ahi[1][KT], BHI, AC[1], 0, 0, 0);   \
    AC[1] = __builtin_amdgcn_mfma_f32_16x16x32_bf16(ahi[1][KT], BLO, AC[1], 0, 0, 0);   \
    AC[1] = __builtin_amdgcn_mfma_f32_16x16x32_bf16(alo[1][KT], BHI, AC[1], 0, 0, 0);   \
    AC[2] = __builtin_amdgcn_mfma_f32_16x16x32_bf16(ahi[2][KT], BHI, AC[2], 0, 0, 0);   \
    AC[2] = __builtin_amdgcn_mfma_f32_16x16x32_bf16(ahi[2][KT], BLO, AC[2], 0, 0, 0);   \
    AC[2] = __builtin_amdgcn_mfma_f32_16x16x32_bf16(alo[2][KT], BHI, AC[2], 0, 0, 0);   \
    AC[3] = __builtin_amdgcn_mfma_f32_16x16x32_bf16(ahi[3][KT], BHI, AC[3], 0, 0, 0);   \
    AC[3] = __builtin_amdgcn_mfma_f32_16x16x32_bf16(ahi[3][KT], BLO, AC[3], 0, 0, 0);   \
    AC[3] = __builtin_amdgcn_mfma_f32_16x16x32_bf16(alo[3][KT], BHI, AC[3], 0, 0, 0);

// ---------------- K2: 2 rows per wave (shared psE loads), 512 blocks -------
// Block = 4 waves: wave = (row-pair rp = wv>>1, j-half h = wv&1).
// Phase A: wave computes rows {rp*2, rp*2+1} over tiles [h*32, h*32+32):
//   per tile ONE psE fragment load feeds BOTH rows' sigmoid+MFMA (2x compute
//   per load -- attacks the measured load-latency stall; R12/R14/R15 showed
//   more waves hurt: L1 thrash, so raise intensity per wave instead).
// Then one barrier; phases B/C/F: wave wv owns row blockIdx*4+wv, VERBATIM
// R14 code (np-exact phase C preserved bit-for-bit).
__global__ __launch_bounds__(256, 2) void pair_topk(
        const float* __restrict__ pm,
        const float* __restrict__ ps,
        const float* __restrict__ psE,
        const float* __restrict__ Mf,
        const float* __restrict__ A,
        float* __restrict__ out) {
    const int tid  = threadIdx.x;
    const int wv   = tid >> 6;           // 0..3
    const int lane = tid & 63;
    const int g    = lane >> 4;          // k-group 0..3
    const int lj   = lane & 15;          // col (B) / row (A) within tile
    const int rp   = wv >> 1;            // row-pair 0..1
    const int h    = wv & 1;             // j-half 0..1

    const int rbase = blockIdx.x * 4;    // first row of block (b-uniform)
    const int b     = rbase >> 10;

    __shared__ uint  d2u[4][NN];         // packed (d2 & ~0x3FF) | j  (16 KB)
    __shared__ float sC[4][C2];
    __shared__ float cdiffL[4][NCAND];

    const float* psb  = ps  + b * NN * C2;
    const float* psEb = psE + b * NN * C2;

    // ---- Phase A: rows r0,r1 over this wave's j-half ----
    {
        const int r0 = rbase + rp * 2;

        float pmEf0[2][8], pmEf1[2][8];
        #pragma unroll
        for (int kt = 0; kt < 2; ++kt) {
            const float4 a0 = *(const float4*)(pm + r0 * C2 + kt * 32 + g * 8);
            const float4 a1 = *(const float4*)(pm + r0 * C2 + kt * 32 + g * 8 + 4);
            pmEf0[kt][0] = EXP2F(a0.x * LOG2E); pmEf0[kt][1] = EXP2F(a0.y * LOG2E);
            pmEf0[kt][2] = EXP2F(a0.z * LOG2E); pmEf0[kt][3] = EXP2F(a0.w * LOG2E);
            pmEf0[kt][4] = EXP2F(a1.x * LOG2E); pmEf0[kt][5] = EXP2F(a1.y * LOG2E);
            pmEf0[kt][6] = EXP2F(a1.z * LOG2E); pmEf0[kt][7] = EXP2F(a1.w * LOG2E);
            const float4 c0 = *(const float4*)(pm + (r0 + 1) * C2 + kt * 32 + g * 8);
            const float4 c1 = *(const float4*)(pm + (r0 + 1) * C2 + kt * 32 + g * 8 + 4);
            pmEf1[kt][0] = EXP2F(c0.x * LOG2E); pmEf1[kt][1] = EXP2F(c0.y * LOG2E);
            pmEf1[kt][2] = EXP2F(c0.z * LOG2E); pmEf1[kt][3] = EXP2F(c0.w * LOG2E);
            pmEf1[kt][4] = EXP2F(c1.x * LOG2E); pmEf1[kt][5] = EXP2F(c1.y * LOG2E);
            pmEf1[kt][6] = EXP2F(c1.z * LOG2E); pmEf1[kt][7] = EXP2F(c1.w * LOG2E);
        }

        short8 ahi[4][2], alo[4][2];     // M rows hi/lo bf16 (RNE, once)
        #pragma unroll
        for (int rt = 0; rt < 4; ++rt) {
            #pragma unroll
            for (int kt = 0; kt < 2; ++kt) {
                const float* mrow = Mf + (rt * 16 + lj) * C2 + kt * 32 + g * 8;
                const float4 m0 = *(const float4*)mrow;
                const float4 m1 = *(const float4*)(mrow + 4);
                float mv[8] = {m0.x, m0.y, m0.z, m0.w, m1.x, m1.y, m1.z, m1.w};
                #pragma unroll
                for (int e = 0; e < 8; ++e) {
                    unsigned short hh = f2bf(mv[e]);
                    ahi[rt][kt][e] = (short)hh;
                    alo[rt][kt][e] = (short)f2bf(mv[e] - bf2f(hh));
                }
            }
        }

        const int tbase = h * 32;
        const float* p0 = psEb + (long)((tbase + 0) * 16 + lj) * C2 + g * 8;
        float4 c0 = *(const float4*)(p0);      float4 c1 = *(const float4*)(p0 + 4);
        float4 c2 = *(const float4*)(p0 + 32); float4 c3 = *(const float4*)(p0 + 36);

        #pragma unroll 1
        for (int it = 0; it < 32; ++it) {
            float4 n0, n1, n2, n3;
            if (it < 31) {                       // issue next-tile loads EARLY
                const float* q0 = psEb + (long)((tbase + it + 1) * 16 + lj) * C2 + g * 8;
                n0 = *(const float4*)(q0);      n1 = *(const float4*)(q0 + 4);
                n2 = *(const float4*)(q0 + 32); n3 = *(const float4*)(q0 + 36);
            }

            // B-fragments for both rows from the SAME loaded psE fragment
            short8 h00, l00, h01, l01;   // row0 kt0/kt1
            short8 h10, l10, h11, l11;   // row1 kt0/kt1
            SIG_PACK(pmEf0, c0, c1, 0, h00, l00);
            SIG_PACK(pmEf0, c2, c3, 1, h01, l01);
            SIG_PACK(pmEf1, c0, c1, 0, h10, l10);
            SIG_PACK(pmEf1, c2, c3, 1, h11, l11);

            f32x4 acc0[4] = {{0,0,0,0},{0,0,0,0},{0,0,0,0},{0,0,0,0}};
            f32x4 acc1[4] = {{0,0,0,0},{0,0,0,0},{0,0,0,0},{0,0,0,0}};

            __builtin_amdgcn_s_setprio(1);
            MFMA12(acc0, 0, h00, l00)
            MFMA12(acc1, 0, h10, l10)
            MFMA12(acc0, 1, h01, l01)
            MFMA12(acc1, 1, h11, l11)
            __builtin_amdgcn_s_setprio(0);

            float sq0 = 0.f, sq1 = 0.f;
            #pragma unroll
            for (int e = 0; e < 4; ++e) {
                sq0 = fmaf(acc0[0][e], acc0[0][e], sq0);
                sq0 = fmaf(acc0[1][e], acc0[1][e], sq0);
                sq0 = fmaf(acc0[2][e], acc0[2][e], sq0);
                sq0 = fmaf(acc0[3][e], acc0[3][e], sq0);
                sq1 = fmaf(acc1[0][e], acc1[0][e], sq1);
                sq1 = fmaf(acc1[1][e], acc1[1][e], sq1);
                sq1 = fmaf(acc1[2][e], acc1[2][e], sq1);
                sq1 = fmaf(acc1[3][e], acc1[3][e], sq1);
            }
            sq0 += __shfl_xor(sq0, 16, 64);
            sq0 += __shfl_xor(sq0, 32, 64);
            sq1 += __shfl_xor(sq1, 16, 64);
            sq1 += __shfl_xor(sq1, 32, 64);
            if (lane < 16) {
                const int jj = (tbase + it) * 16 + lane;
                d2u[rp * 2 + 0][jj] = (__float_as_uint(sq0) & 0xFFFFFC00u) | (uint)jj;
                d2u[rp * 2 + 1][jj] = (__float_as_uint(sq1) & 0xFFFFFC00u) | (uint)jj;
            }

            c0 = n0; c1 = n1; c2 = n2; c3 = n3;
        }
    }
    __syncthreads();

    // ---- Phases B/C/F: wave wv owns row rbase+wv (VERBATIM R14 path) ----
    const int bi = rbase + wv;
    const int i  = bi & (NN - 1);
    const float pm_own = pm[bi * C2 + lane];

    // Phase B: top-24 via packed-uint min passes
    uint v[16];
    #pragma unroll
    for (int q = 0; q < 16; ++q) v[q] = d2u[wv][q * 64 + lane];

    int myCand = 0;
    #pragma unroll 1
    for (int k = 0; k < NCAND; ++k) {
        uint bv = v[0];
        #pragma unroll
        for (int q = 1; q < 16; ++q) bv = min(bv, v[q]);
        #pragma unroll
        for (int st = 0; st < 6; ++st)
            bv = min(bv, (uint)__shfl_xor((int)bv, 1 << st, 64));
        #pragma unroll
        for (int q = 0; q < 16; ++q)
            if (v[q] == bv) v[q] = 0xFFFFFFFFu;
        if (lane == k) myCand = (int)(bv & 0x3FFu);
    }

    // Phase C: np-exact rescore (R6 bit-exact), 24 candidates
    float Acol[C2];
    #pragma unroll
    for (int c = 0; c < C2; ++c) Acol[c] = A[c * C2 + lane];

    #pragma unroll 1
    for (int t = 0; t < NCAND; ++t) {
        const int j = __shfl(myCand, t, 64);
        float psc = psb[(long)j * C2 + lane];
        float e = expf(psc - pm_own);
        float s_own = 1.0f / __fadd_rn(1.0f, e);     // sigmoid(pm-ps), lane=c
        sC[wv][lane] = s_own;
        LDS_FENCE();
        float wd = 0.f;
        #pragma unroll
        for (int c = 0; c < C2; ++c)                 // ascending c, single acc
            wd = fmaf(sC[wv][c], Acol[c], wd);
        const float t_own = __fmul_rn(wd, s_own);    // t_d = w_d * s_d, lane=d
        // numpy pairwise-8 via shfl (same op order as np)
        float r8 = t_own;
        #pragma unroll
        for (int blk = 1; blk < 8; ++blk)
            r8 = __fadd_rn(r8, __shfl(t_own, (lane & 7) + 8 * blk, 64));
        const float rr0 = __shfl(r8, 0, 64), rr1 = __shfl(r8, 1, 64);
        const float rr2 = __shfl(r8, 2, 64), rr3 = __shfl(r8, 3, 64);
        const float rr4 = __shfl(r8, 4, 64), rr5 = __shfl(r8, 5, 64);
        const float rr6 = __shfl(r8, 6, 64), rr7 = __shfl(r8, 7, 64);
        float dis2 = __fadd_rn(
            __fadd_rn(__fadd_rn(rr0, rr1), __fadd_rn(rr2, rr3)),
            __fadd_rn(__fadd_rn(rr4, rr5), __fadd_rn(rr6, rr7)));
        float disf = sqrtf(dis2);
        float ee = expf(disf);
        float cd = 1.0f / __fadd_rn(1.0f, ee);       // sigmoid(-dis)
        if (lane == 0) cdiffL[wv][t] = cd;
    }
    LDS_FENCE();

    // Final: per-wave top-16 over 24 exact diffs (desc, index asc)
    float myd = (lane < NCAND) ? cdiffL[wv][lane] : -2.0f;
    int myj = (lane < NCAND) ? myCand : (1 << 20);

    const int obase = b * (NN * KK) + i * KK;        // index chunk (f32)
    const int vbase = 2 * NN * KK + obase;           // value chunk (f32)

    #pragma unroll 1
    for (int k = 0; k < KK; ++k) {
        float bd = myd;
        int bj = myj;
        #pragma unroll
        for (int st = 0; st < 6; ++st) {
            int msk = 1 << st;
            float od = __shfl_xor(bd, msk, 64);
            int oj = __shfl_xor(bj, msk, 64);
            bool better = (od > bd) || (od == bd && oj < bj);
            bd = better ? od : bd;
            bj = better ? oj : bj;
        }
        if (myj == bj) myd = -2.0f;                  // candidate j's unique
        if (lane == 0) {
            out[obase + k] = (float)bj;
            out[vbase + k] = -bd;                    // value = -topk(diff)
        }
    }
}

extern "C" void kernel_launch(void* const* d_in, const int* in_sizes, int n_in,
                              void* d_out, int out_size, void* d_ws, size_t ws_size,
                              hipStream_t stream) {
    const float* X  = (const float*)d_in[0];
    const float* Wm = (const float*)d_in[1];
    const float* Ws = (const float*)d_in[2];
    const float* M  = (const float*)d_in[3];

    float* A   = (float*)d_ws;           // 4096 f   (16 KB)
    float* pm  = A + C2 * C2;            // 131072 f (512 KB)
    float* ps  = pm + 2 * NN * C2;       // 131072 f (512 KB)
    float* psE = ps + 2 * NN * C2;       // 131072 f (512 KB)  total ~1.52 MB
    float* out = (float*)d_out;          // f32: [idx 32768][val 32768]

    hipLaunchKernelGGL(buildA, dim3(16), dim3(256), 0, stream, M, A);
    hipLaunchKernelGGL(proj, dim3(2 * NN), dim3(128), 0, stream,
                       X, Wm, Ws, pm, ps, psE);
    hipLaunchKernelGGL(pair_topk, dim3(512), dim3(256), 0, stream,
                       pm, ps, psE, M, A, out);
}

// Round 17
// 110.298 us; speedup vs baseline: 1.2977x; 1.0633x over previous
//
#include <hip/hip_runtime.h>
#include <hip/hip_bf16.h>
#include <math.h>

#define NN 1024
#define CC 128
#define C2 64
#define KK 16
#define NCAND 20

#if __has_builtin(__builtin_amdgcn_exp2f)
#define EXP2F(x) __builtin_amdgcn_exp2f(x)
#else
#define EXP2F(x) exp2f(x)
#endif
#define LOG2E 1.4426950408889634f

typedef short short8 __attribute__((ext_vector_type(8)));
typedef float f32x4  __attribute__((ext_vector_type(4)));
typedef int   int4v  __attribute__((ext_vector_type(4)));
typedef unsigned int uint;

__device__ __forceinline__ float fast_rcp(float x) {
    return __builtin_amdgcn_rcpf(x);
}
__device__ __forceinline__ unsigned short f2bf(float x) {   // RNE f32->bf16
    unsigned int u = __float_as_uint(x);
    unsigned int r = (u + 0x7FFFu + ((u >> 16) & 1u)) >> 16;
    return (unsigned short)r;
}
__device__ __forceinline__ float bf2f(unsigned short h) {
    return __uint_as_float(((unsigned int)h) << 16);
}

// In-wave LDS write->read visibility: wait LDS ops, pin compiler order.
#define LDS_FENCE() do { \
    asm volatile("s_waitcnt lgkmcnt(0)" ::: "memory"); \
    __builtin_amdgcn_sched_barrier(0); } while (0)

// ---------------- K0: A = M^T M, f32, ascending-r fmaf chain (np-exact) ----
__global__ __launch_bounds__(256) void buildA(const float* __restrict__ M,
                                              float* __restrict__ A) {
    const int e = blockIdx.x * 256 + threadIdx.x;    // 4096 entries
    const int c = e >> 6, d = e & 63;
    float acc = 0.f;
    #pragma unroll 8
    for (int r = 0; r < C2; ++r)
        acc = fmaf(M[r * C2 + c], M[r * C2 + d], acc);
    A[e] = acc;                                      // A[c][d] row-major
}

// ---------------- K1: projections + logmap, f32 (np-exact) + psE -----------
__global__ __launch_bounds__(128) void proj(
        const float* __restrict__ X,
        const float* __restrict__ Wm,
        const float* __restrict__ Ws,
        float* __restrict__ pm,
        float* __restrict__ ps,
        float* __restrict__ psE) {
    const int bn = blockIdx.x;           // b*1024 + n
    const int b  = bn >> 10;
    const int n  = bn & (NN - 1);
    const int t  = threadIdx.x;          // 0..127

    __shared__ float xv[CC];
    xv[t] = X[b * CC * NN + t * NN + n];
    __syncthreads();

    const int d = t & (C2 - 1);
    const float* wr = ((t < C2) ? Wm : Ws) + d * CC;
    float acc = 0.f;
    #pragma unroll
    for (int c = 0; c < CC; ++c)
        acc = fmaf(wr[c], xv[c], acc);   // sequential k-order, single acc

    float a = __fadd_rn(fabsf(acc), 1e-10f);
    float l = logf(a);
    float r = (acc > 0.f) ? l : ((acc < 0.f) ? -l : 0.f);
    if (t < C2) {
        pm[bn * C2 + d] = r;
    } else {
        ps[bn * C2 + d] = r;
        psE[bn * C2 + d] = EXP2F(r * LOG2E);   // e^ps (proxy pass only)
    }
}

// Build bhi/blo bf16 fragments from 8 sigmoids (truncation split; proxy only)
#define SIG_PACK(PMEF, Y0, Y1, KT, BHI, BLO) do {                             \
    float s0 = PMEF[KT][0] * fast_rcp(PMEF[KT][0] + (Y0).x);                  \
    float s1 = PMEF[KT][1] * fast_rcp(PMEF[KT][1] + (Y0).y);                  \
    float s2 = PMEF[KT][2] * fast_rcp(PMEF[KT][2] + (Y0).z);                  \
    float s3 = PMEF[KT][3] * fast_rcp(PMEF[KT][3] + (Y0).w);                  \
    float s4 = PMEF[KT][4] * fast_rcp(PMEF[KT][4] + (Y1).x);                  \
    float s5 = PMEF[KT][5] * fast_rcp(PMEF[KT][5] + (Y1).y);                  \
    float s6 = PMEF[KT][6] * fast_rcp(PMEF[KT][6] + (Y1).z);                  \
    float s7 = PMEF[KT][7] * fast_rcp(PMEF[KT][7] + (Y1).w);                  \
    uint u0 = __float_as_uint(s0), u1 = __float_as_uint(s1);                  \
    uint u2 = __float_as_uint(s2), u3 = __float_as_uint(s3);                  \
    uint u4 = __float_as_uint(s4), u5 = __float_as_uint(s5);                  \
    uint u6 = __float_as_uint(s6), u7 = __float_as_uint(s7);                  \
    uint l0 = __float_as_uint(s0 - __uint_as_float(u0 & 0xFFFF0000u));        \
    uint l1 = __float_as_uint(s1 - __uint_as_float(u1 & 0xFFFF0000u));        \
    uint l2 = __float_as_uint(s2 - __uint_as_float(u2 & 0xFFFF0000u));        \
    uint l3 = __float_as_uint(s3 - __uint_as_float(u3 & 0xFFFF0000u));        \
    uint l4 = __float_as_uint(s4 - __uint_as_float(u4 & 0xFFFF0000u));        \
    uint l5 = __float_as_uint(s5 - __uint_as_float(u5 & 0xFFFF0000u));        \
    uint l6 = __float_as_uint(s6 - __uint_as_float(u6 & 0xFFFF0000u));        \
    uint l7 = __float_as_uint(s7 - __uint_as_float(u7 & 0xFFFF0000u));        \
    int4v hiv = { (int)__builtin_amdgcn_perm(u1, u0, 0x07060302u),            \
                  (int)__builtin_amdgcn_perm(u3, u2, 0x07060302u),            \
                  (int)__builtin_amdgcn_perm(u5, u4, 0x07060302u),            \
                  (int)__builtin_amdgcn_perm(u7, u6, 0x07060302u) };          \
    int4v lov = { (int)__builtin_amdgcn_perm(l1, l0, 0x07060302u),            \
                  (int)__builtin_amdgcn_perm(l3, l2, 0x07060302u),            \
                  (int)__builtin_amdgcn_perm(l5, l4, 0x07060302u),            \
                  (int)__builtin_amdgcn_perm(l7, l6, 0x07060302u) };          \
    BHI = __builtin_bit_cast(short8, hiv);                                    \
    BLO = __builtin_bit_cast(short8, lov);                                    \
} while (0)

#define MFMA12(AC, KT, BHI, BLO)                                                        \
    AC[0] = __builtin_amdgcn_mfma_f32_16x16x32_bf16(ahi[0][KT], BHI, AC[0], 0, 0, 0);   \
    AC[0] = __builtin_amdgcn_mfma_f32_16x16x32_bf16(ahi[0][KT], BLO, AC[0], 0, 0, 0);   \
    AC[0] = __builtin_amdgcn_mfma_f32_16x16x32_bf16(alo[0][KT], BHI, AC[0], 0, 0, 0);   \
    AC[1] = __builtin_amdgcn_mfma_f32_16x16x32_bf16(ahi[1][KT], BHI, AC[1], 0, 0, 0);   \
    AC[1] = __builtin_amdgcn_mfma_f32_16x16x32_bf16(ahi[1][KT], BLO, AC[1], 0, 0, 0);   \
    AC[1] = __builtin_amdgcn_mfma_f32_16x16x32_bf16(alo[1][KT], BHI, AC[1], 0, 0, 0);   \
    AC[2] = __builtin_amdgcn_mfma_f32_16x16x32_bf16(ahi[2][KT], BHI, AC[2], 0, 0, 0);   \
    AC[2] = __builtin_amdgcn_mfma_f32_16x16x32_bf16(ahi[2][KT], BLO, AC[2], 0, 0, 0);   \
    AC[2] = __builtin_amdgcn_mfma_f32_16x16x32_bf16(alo[2][KT], BHI, AC[2], 0, 0, 0);   \
    AC[3] = __builtin_amdgcn_mfma_f32_16x16x32_bf16(ahi[3][KT], BHI, AC[3], 0, 0, 0);   \
    AC[3] = __builtin_amdgcn_mfma_f32_16x16x32_bf16(ahi[3][KT], BLO, AC[3], 0, 0, 0);   \
    AC[3] = __builtin_amdgcn_mfma_f32_16x16x32_bf16(alo[3][KT], BHI, AC[3], 0, 0, 0);

// One stream: pack both kt fragments then 24 MFMA (keeps <=4 B-frags live)
#define STREAM(PMEF, T0, T1, T2, T3, AC) do {                                 \
    short8 bh0, bl0, bh1, bl1;                                                \
    SIG_PACK(PMEF, T0, T1, 0, bh0, bl0);                                      \
    SIG_PACK(PMEF, T2, T3, 1, bh1, bl1);                                      \
    MFMA12(AC, 0, bh0, bl0)                                                   \
    MFMA12(AC, 1, bh1, bl1)                                                   \
} while (0)

// ---------------- K2: 2 rows x 2 tiles per wave iter, 512 blocks -----------
// Block = 4 waves: wave = (row-pair rp = wv>>1, j-half h = wv&1).
// Phase A: wave computes rows {rp*2, rp*2+1} over 16 iters x 2 tiles:
//   per iter TWO psE tile loads feed FOUR independent pack->MFMA->square
//   streams (2 rows x 2 tiles) -- R16's load sharing + R13's tile ILP.
// Phases B/C/F: wave wv owns row rbase+wv, R14 path (np-exact phase C).
__global__ __launch_bounds__(256, 2) void pair_topk(
        const float* __restrict__ pm,
        const float* __restrict__ ps,
        const float* __restrict__ psE,
        const float* __restrict__ Mf,
        const float* __restrict__ A,
        float* __restrict__ out) {
    const int tid  = threadIdx.x;
    const int wv   = tid >> 6;           // 0..3
    const int lane = tid & 63;
    const int g    = lane >> 4;          // k-group 0..3
    const int lj   = lane & 15;          // col (B) / row (A) within tile
    const int rp   = wv >> 1;            // row-pair 0..1
    const int h    = wv & 1;             // j-half 0..1

    const int rbase = blockIdx.x * 4;    // first row of block (b-uniform)
    const int b     = rbase >> 10;

    __shared__ uint  d2u[4][NN];         // packed (d2 & ~0x3FF) | j  (16 KB)
    __shared__ float sC[4][C2];
    __shared__ float cdiffL[4][NCAND];

    const float* psb  = ps  + b * NN * C2;
    const float* psEb = psE + b * NN * C2;

    // ---- Phase A: rows r0,r1 over this wave's j-half, 2 tiles/iter ----
    {
        const int r0 = rbase + rp * 2;

        float pmEf0[2][8], pmEf1[2][8];
        #pragma unroll
        for (int kt = 0; kt < 2; ++kt) {
            const float4 a0 = *(const float4*)(pm + r0 * C2 + kt * 32 + g * 8);
            const float4 a1 = *(const float4*)(pm + r0 * C2 + kt * 32 + g * 8 + 4);
            pmEf0[kt][0] = EXP2F(a0.x * LOG2E); pmEf0[kt][1] = EXP2F(a0.y * LOG2E);
            pmEf0[kt][2] = EXP2F(a0.z * LOG2E); pmEf0[kt][3] = EXP2F(a0.w * LOG2E);
            pmEf0[kt][4] = EXP2F(a1.x * LOG2E); pmEf0[kt][5] = EXP2F(a1.y * LOG2E);
            pmEf0[kt][6] = EXP2F(a1.z * LOG2E); pmEf0[kt][7] = EXP2F(a1.w * LOG2E);
            const float4 c0 = *(const float4*)(pm + (r0 + 1) * C2 + kt * 32 + g * 8);
            const float4 c1 = *(const float4*)(pm + (r0 + 1) * C2 + kt * 32 + g * 8 + 4);
            pmEf1[kt][0] = EXP2F(c0.x * LOG2E); pmEf1[kt][1] = EXP2F(c0.y * LOG2E);
            pmEf1[kt][2] = EXP2F(c0.z * LOG2E); pmEf1[kt][3] = EXP2F(c0.w * LOG2E);
            pmEf1[kt][4] = EXP2F(c1.x * LOG2E); pmEf1[kt][5] = EXP2F(c1.y * LOG2E);
            pmEf1[kt][6] = EXP2F(c1.z * LOG2E); pmEf1[kt][7] = EXP2F(c1.w * LOG2E);
        }

        short8 ahi[4][2], alo[4][2];     // M rows hi/lo bf16 (RNE, once)
        #pragma unroll
        for (int rt = 0; rt < 4; ++rt) {
            #pragma unroll
            for (int kt = 0; kt < 2; ++kt) {
                const float* mrow = Mf + (rt * 16 + lj) * C2 + kt * 32 + g * 8;
                const float4 m0 = *(const float4*)mrow;
                const float4 m1 = *(const float4*)(mrow + 4);
                float mv[8] = {m0.x, m0.y, m0.z, m0.w, m1.x, m1.y, m1.z, m1.w};
                #pragma unroll
                for (int e = 0; e < 8; ++e) {
                    unsigned short hh = f2bf(mv[e]);
                    ahi[rt][kt][e] = (short)hh;
                    alo[rt][kt][e] = (short)f2bf(mv[e] - bf2f(hh));
                }
            }
        }

        const int tbase = h * 32;
        const float* p0 = psEb + (long)((tbase + 0) * 16 + lj) * C2 + g * 8;
        const float* p1 = psEb + (long)((tbase + 1) * 16 + lj) * C2 + g * 8;
        float4 cA0 = *(const float4*)(p0);      float4 cA1 = *(const float4*)(p0 + 4);
        float4 cA2 = *(const float4*)(p0 + 32); float4 cA3 = *(const float4*)(p0 + 36);
        float4 cB0 = *(const float4*)(p1);      float4 cB1 = *(const float4*)(p1 + 4);
        float4 cB2 = *(const float4*)(p1 + 32); float4 cB3 = *(const float4*)(p1 + 36);

        #pragma unroll 1
        for (int it = 0; it < 16; ++it) {
            float4 nA0, nA1, nA2, nA3, nB0, nB1, nB2, nB3;
            if (it < 15) {                       // issue next-iter loads EARLY
                const float* q0 = psEb + (long)((tbase + it * 2 + 2) * 16 + lj) * C2 + g * 8;
                const float* q1 = psEb + (long)((tbase + it * 2 + 3) * 16 + lj) * C2 + g * 8;
                nA0 = *(const float4*)(q0);      nA1 = *(const float4*)(q0 + 4);
                nA2 = *(const float4*)(q0 + 32); nA3 = *(const float4*)(q0 + 36);
                nB0 = *(const float4*)(q1);      nB1 = *(const float4*)(q1 + 4);
                nB2 = *(const float4*)(q1 + 32); nB3 = *(const float4*)(q1 + 36);
            }

            f32x4 a0A[4] = {{0,0,0,0},{0,0,0,0},{0,0,0,0},{0,0,0,0}};
            f32x4 a1A[4] = {{0,0,0,0},{0,0,0,0},{0,0,0,0},{0,0,0,0}};
            f32x4 a0B[4] = {{0,0,0,0},{0,0,0,0},{0,0,0,0},{0,0,0,0}};
            f32x4 a1B[4] = {{0,0,0,0},{0,0,0,0},{0,0,0,0},{0,0,0,0}};

            __builtin_amdgcn_s_setprio(1);
            STREAM(pmEf0, cA0, cA1, cA2, cA3, a0A);
            STREAM(pmEf1, cA0, cA1, cA2, cA3, a1A);
            STREAM(pmEf0, cB0, cB1, cB2, cB3, a0B);
            STREAM(pmEf1, cB0, cB1, cB2, cB3, a1B);
            __builtin_amdgcn_s_setprio(0);

            float s0A = 0.f, s1A = 0.f, s0B = 0.f, s1B = 0.f;
            #pragma unroll
            for (int e = 0; e < 4; ++e) {
                s0A = fmaf(a0A[0][e], a0A[0][e], s0A);
                s0A = fmaf(a0A[1][e], a0A[1][e], s0A);
                s0A = fmaf(a0A[2][e], a0A[2][e], s0A);
                s0A = fmaf(a0A[3][e], a0A[3][e], s0A);
                s1A = fmaf(a1A[0][e], a1A[0][e], s1A);
                s1A = fmaf(a1A[1][e], a1A[1][e], s1A);
                s1A = fmaf(a1A[2][e], a1A[2][e], s1A);
                s1A = fmaf(a1A[3][e], a1A[3][e], s1A);
                s0B = fmaf(a0B[0][e], a0B[0][e], s0B);
                s0B = fmaf(a0B[1][e], a0B[1][e], s0B);
                s0B = fmaf(a0B[2][e], a0B[2][e], s0B);
                s0B = fmaf(a0B[3][e], a0B[3][e], s0B);
                s1B = fmaf(a1B[0][e], a1B[0][e], s1B);
                s1B = fmaf(a1B[1][e], a1B[1][e], s1B);
                s1B = fmaf(a1B[2][e], a1B[2][e], s1B);
                s1B = fmaf(a1B[3][e], a1B[3][e], s1B);
            }
            s0A += __shfl_xor(s0A, 16, 64); s0A += __shfl_xor(s0A, 32, 64);
            s1A += __shfl_xor(s1A, 16, 64); s1A += __shfl_xor(s1A, 32, 64);
            s0B += __shfl_xor(s0B, 16, 64); s0B += __shfl_xor(s0B, 32, 64);
            s1B += __shfl_xor(s1B, 16, 64); s1B += __shfl_xor(s1B, 32, 64);
            if (lane < 16) {
                const int jA = (tbase + it * 2 + 0) * 16 + lane;
                const int jB = (tbase + it * 2 + 1) * 16 + lane;
                d2u[rp * 2 + 0][jA] = (__float_as_uint(s0A) & 0xFFFFFC00u) | (uint)jA;
                d2u[rp * 2 + 1][jA] = (__float_as_uint(s1A) & 0xFFFFFC00u) | (uint)jA;
                d2u[rp * 2 + 0][jB] = (__float_as_uint(s0B) & 0xFFFFFC00u) | (uint)jB;
                d2u[rp * 2 + 1][jB] = (__float_as_uint(s1B) & 0xFFFFFC00u) | (uint)jB;
            }

            cA0 = nA0; cA1 = nA1; cA2 = nA2; cA3 = nA3;
            cB0 = nB0; cB1 = nB1; cB2 = nB2; cB3 = nB3;
        }
    }
    __syncthreads();

    // ---- Phases B/C/F: wave wv owns row rbase+wv (R14 path) ----
    const int bi = rbase + wv;
    const int i  = bi & (NN - 1);
    const float pm_own = pm[bi * C2 + lane];

    // Phase B: top-NCAND via packed-uint min passes
    uint v[16];
    #pragma unroll
    for (int q = 0; q < 16; ++q) v[q] = d2u[wv][q * 64 + lane];

    int myCand = 0;
    #pragma unroll 1
    for (int k = 0; k < NCAND; ++k) {
        uint bv = v[0];
        #pragma unroll
        for (int q = 1; q < 16; ++q) bv = min(bv, v[q]);
        #pragma unroll
        for (int st = 0; st < 6; ++st)
            bv = min(bv, (uint)__shfl_xor((int)bv, 1 << st, 64));
        #pragma unroll
        for (int q = 0; q < 16; ++q)
            if (v[q] == bv) v[q] = 0xFFFFFFFFu;
        if (lane == k) myCand = (int)(bv & 0x3FFu);
    }

    // Phase C: np-exact rescore (R6 bit-exact), NCAND candidates,
    // candidate ps loads batched upfront (hide L2 latency).
    float Acol[C2];
    #pragma unroll
    for (int c = 0; c < C2; ++c) Acol[c] = A[c * C2 + lane];

    int jvv[NCAND];
    #pragma unroll
    for (int t = 0; t < NCAND; ++t) jvv[t] = __shfl(myCand, t, 64);
    float pscv[NCAND];
    #pragma unroll
    for (int t = 0; t < NCAND; ++t) pscv[t] = psb[(long)jvv[t] * C2 + lane];

    #pragma unroll 1
    for (int t = 0; t < NCAND; ++t) {
        float e = expf(pscv[t] - pm_own);
        float s_own = 1.0f / __fadd_rn(1.0f, e);     // sigmoid(pm-ps), lane=c
        sC[wv][lane] = s_own;
        LDS_FENCE();
        float wd = 0.f;
        #pragma unroll
        for (int c = 0; c < C2; ++c)                 // ascending c, single acc
            wd = fmaf(sC[wv][c], Acol[c], wd);
        const float t_own = __fmul_rn(wd, s_own);    // t_d = w_d * s_d, lane=d
        // numpy pairwise-8 via shfl (same op order as np)
        float r8 = t_own;
        #pragma unroll
        for (int blk = 1; blk < 8; ++blk)
            r8 = __fadd_rn(r8, __shfl(t_own, (lane & 7) + 8 * blk, 64));
        const float rr0 = __shfl(r8, 0, 64), rr1 = __shfl(r8, 1, 64);
        const float rr2 = __shfl(r8, 2, 64), rr3 = __shfl(r8, 3, 64);
        const float rr4 = __shfl(r8, 4, 64), rr5 = __shfl(r8, 5, 64);
        const float rr6 = __shfl(r8, 6, 64), rr7 = __shfl(r8, 7, 64);
        float dis2 = __fadd_rn(
            __fadd_rn(__fadd_rn(rr0, rr1), __fadd_rn(rr2, rr3)),
            __fadd_rn(__fadd_rn(rr4, rr5), __fadd_rn(rr6, rr7)));
        float disf = sqrtf(dis2);
        float ee = expf(disf);
        float cd = 1.0f / __fadd_rn(1.0f, ee);       // sigmoid(-dis)
        if (lane == 0) cdiffL[wv][t] = cd;
    }
    LDS_FENCE();

    // Final: per-wave top-16 over NCAND exact diffs (desc, index asc)
    float myd = (lane < NCAND) ? cdiffL[wv][lane] : -2.0f;
    int myj = (lane < NCAND) ? myCand : (1 << 20);

    const int obase = b * (NN * KK) + i * KK;        // index chunk (f32)
    const int vbase = 2 * NN * KK + obase;           // value chunk (f32)

    #pragma unroll 1
    for (int k = 0; k < KK; ++k) {
        float bd = myd;
        int bj = myj;
        #pragma unroll
        for (int st = 0; st < 6; ++st) {
            int msk = 1 << st;
            float od = __shfl_xor(bd, msk, 64);
            int oj = __shfl_xor(bj, msk, 64);
            bool better = (od > bd) || (od == bd && oj < bj);
            bd = better ? od : bd;
            bj = better ? oj : bj;
        }
        if (myj == bj) myd = -2.0f;                  // candidate j's unique
        if (lane == 0) {
            out[obase + k] = (float)bj;
            out[vbase + k] = -bd;                    // value = -topk(diff)
        }
    }
}

extern "C" void kernel_launch(void* const* d_in, const int* in_sizes, int n_in,
                              void* d_out, int out_size, void* d_ws, size_t ws_size,
                              hipStream_t stream) {
    const float* X  = (const float*)d_in[0];
    const float* Wm = (const float*)d_in[1];
    const float* Ws = (const float*)d_in[2];
    const float* M  = (const float*)d_in[3];

    float* A   = (float*)d_ws;           // 4096 f   (16 KB)
    float* pm  = A + C2 * C2;            // 131072 f (512 KB)
    float* ps  = pm + 2 * NN * C2;       // 131072 f (512 KB)
    float* psE = ps + 2 * NN * C2;       // 131072 f (512 KB)  total ~1.52 MB
    float* out = (float*)d_out;          // f32: [idx 32768][val 32768]

    hipLaunchKernelGGL(buildA, dim3(16), dim3(256), 0, stream, M, A);
    hipLaunchKernelGGL(proj, dim3(2 * NN), dim3(128), 0, stream,
                       X, Wm, Ws, pm, ps, psE);
    hipLaunchKernelGGL(pair_topk, dim3(512), dim3(256), 0, stream,
                       pm, ps, psE, M, A, out);
}

// Round 19
// 98.861 us; speedup vs baseline: 1.4478x; 1.1157x over previous
//
#include <hip/hip_runtime.h>
#include <hip/hip_bf16.h>
#include <hip/hip_fp16.h>
#include <math.h>

#define NN 1024
#define CC 128
#define C2 64
#define KK 16
#define NCAND 24

#if __has_builtin(__builtin_amdgcn_exp2f)
#define EXP2F(x) __builtin_amdgcn_exp2f(x)
#else
#define EXP2F(x) exp2f(x)
#endif
#define LOG2E 1.4426950408889634f

typedef __fp16  hf2   __attribute__((ext_vector_type(2)));   // cvt_pkrtz result type
typedef _Float16 half8 __attribute__((ext_vector_type(8)));  // MFMA operand type
typedef float f32x4    __attribute__((ext_vector_type(4)));
typedef int   int4v    __attribute__((ext_vector_type(4)));
typedef unsigned int uint;

__device__ __forceinline__ float fast_rcp(float x) {
    return __builtin_amdgcn_rcpf(x);
}

// In-wave LDS write->read visibility: wait LDS ops, pin compiler order.
#define LDS_FENCE() do { \
    asm volatile("s_waitcnt lgkmcnt(0)" ::: "memory"); \
    __builtin_amdgcn_sched_barrier(0); } while (0)

// ---------------- K1: proj (np-exact) + psE, fused with buildA -------------
// blocks [0, 2*NN): proj; blocks [2*NN, 2*NN+32): A = M^T M.
__global__ __launch_bounds__(128) void proj_buildA(
        const float* __restrict__ X,
        const float* __restrict__ Wm,
        const float* __restrict__ Ws,
        const float* __restrict__ M,
        float* __restrict__ pm,
        float* __restrict__ ps,
        float* __restrict__ psE,
        float* __restrict__ A) {
    if (blockIdx.x >= 2 * NN) {          // ---- buildA: 32 blocks x 128 thr
        const int e = (blockIdx.x - 2 * NN) * 128 + threadIdx.x;  // < 4096
        const int c = e >> 6, d = e & 63;
        float acc = 0.f;
        #pragma unroll 8
        for (int r = 0; r < C2; ++r)
            acc = fmaf(M[r * C2 + c], M[r * C2 + d], acc);
        A[e] = acc;                      // A[c][d] row-major
        return;
    }

    const int bn = blockIdx.x;           // b*1024 + n
    const int b  = bn >> 10;
    const int n  = bn & (NN - 1);
    const int t  = threadIdx.x;          // 0..127

    __shared__ float xv[CC];
    xv[t] = X[b * CC * NN + t * NN + n];
    __syncthreads();

    const int d = t & (C2 - 1);
    const float* wr = ((t < C2) ? Wm : Ws) + d * CC;
    float acc = 0.f;
    #pragma unroll
    for (int c = 0; c < CC; ++c)
        acc = fmaf(wr[c], xv[c], acc);   // sequential k-order, single acc

    float a = __fadd_rn(fabsf(acc), 1e-10f);
    float l = logf(a);
    float r = (acc > 0.f) ? l : ((acc < 0.f) ? -l : 0.f);
    if (t < C2) {
        pm[bn * C2 + d] = r;
    } else {
        ps[bn * C2 + d] = r;
        psE[bn * C2 + d] = EXP2F(r * LOG2E);   // e^ps (proxy pass only)
    }
}

// f32 sigmoid -> packed fp16 B-fragment (single term; proxy only).
// cvt_pkrtz packs 2 f32 -> 2 f16 (RTZ) in ONE VALU op: no split/pack chain.
#define SIGF16(PMEF, Y0, Y1, BF) do {                                         \
    float s0 = PMEF[0] * fast_rcp(PMEF[0] + (Y0).x);                          \
    float s1 = PMEF[1] * fast_rcp(PMEF[1] + (Y0).y);                          \
    float s2 = PMEF[2] * fast_rcp(PMEF[2] + (Y0).z);                          \
    float s3 = PMEF[3] * fast_rcp(PMEF[3] + (Y0).w);                          \
    float s4 = PMEF[4] * fast_rcp(PMEF[4] + (Y1).x);                          \
    float s5 = PMEF[5] * fast_rcp(PMEF[5] + (Y1).y);                          \
    float s6 = PMEF[6] * fast_rcp(PMEF[6] + (Y1).z);                          \
    float s7 = PMEF[7] * fast_rcp(PMEF[7] + (Y1).w);                          \
    hf2 p0 = __builtin_amdgcn_cvt_pkrtz(s0, s1);                              \
    hf2 p1 = __builtin_amdgcn_cvt_pkrtz(s2, s3);                              \
    hf2 p2 = __builtin_amdgcn_cvt_pkrtz(s4, s5);                              \
    hf2 p3 = __builtin_amdgcn_cvt_pkrtz(s6, s7);                              \
    int4v iv = { __builtin_bit_cast(int, p0), __builtin_bit_cast(int, p1),    \
                 __builtin_bit_cast(int, p2), __builtin_bit_cast(int, p3) };  \
    BF = __builtin_bit_cast(half8, iv);                                       \
} while (0)

// 2-term A-split (Mhi+Mlo fp16), single-term B: 8 MFMA per kt-fragment.
#define MFMA8(AC, KT, B)                                                                \
    AC[0] = __builtin_amdgcn_mfma_f32_16x16x32_f16(ahi[0][KT], B, AC[0], 0, 0, 0);      \
    AC[0] = __builtin_amdgcn_mfma_f32_16x16x32_f16(alo[0][KT], B, AC[0], 0, 0, 0);      \
    AC[1] = __builtin_amdgcn_mfma_f32_16x16x32_f16(ahi[1][KT], B, AC[1], 0, 0, 0);      \
    AC[1] = __builtin_amdgcn_mfma_f32_16x16x32_f16(alo[1][KT], B, AC[1], 0, 0, 0);      \
    AC[2] = __builtin_amdgcn_mfma_f32_16x16x32_f16(ahi[2][KT], B, AC[2], 0, 0, 0);      \
    AC[2] = __builtin_amdgcn_mfma_f32_16x16x32_f16(alo[2][KT], B, AC[2], 0, 0, 0);      \
    AC[3] = __builtin_amdgcn_mfma_f32_16x16x32_f16(ahi[3][KT], B, AC[3], 0, 0, 0);      \
    AC[3] = __builtin_amdgcn_mfma_f32_16x16x32_f16(alo[3][KT], B, AC[3], 0, 0, 0);

// One stream: build 2 fp16 B-fragments, 16 MFMA
#define STREAM(PMEF, T0, T1, T2, T3, AC) do {                                 \
    half8 b0, b1;                                                             \
    SIGF16(PMEF[0], T0, T1, b0);                                              \
    SIGF16(PMEF[1], T2, T3, b1);                                              \
    MFMA8(AC, 0, b0)                                                          \
    MFMA8(AC, 1, b1)                                                          \
} while (0)

// ---------------- K2: 2 rows x 2 tiles per wave iter, 512 blocks -----------
// Block = 4 waves: wave = (row-pair rp = wv>>1, j-half h = wv&1).
// Phase A: fp16 proxy (A 2-term split, B single fp16 via cvt_pkrtz).
// Phases B/C/F: wave wv owns row rbase+wv, R14 path (np-exact phase C).
__global__ __launch_bounds__(256, 2) void pair_topk(
        const float* __restrict__ pm,
        const float* __restrict__ ps,
        const float* __restrict__ psE,
        const float* __restrict__ Mf,
        const float* __restrict__ A,
        float* __restrict__ out) {
    const int tid  = threadIdx.x;
    const int wv   = tid >> 6;           // 0..3
    const int lane = tid & 63;
    const int g    = lane >> 4;          // k-group 0..3
    const int lj   = lane & 15;          // col (B) / row (A) within tile
    const int rp   = wv >> 1;            // row-pair 0..1
    const int h    = wv & 1;             // j-half 0..1

    const int rbase = blockIdx.x * 4;    // first row of block (b-uniform)
    const int b     = rbase >> 10;

    __shared__ uint  d2u[4][NN];         // packed (d2 & ~0x3FF) | j  (16 KB)
    __shared__ float sC[4][C2];
    __shared__ float cdiffL[4][NCAND];

    const float* psb  = ps  + b * NN * C2;
    const float* psEb = psE + b * NN * C2;

    // ---- Phase A: rows r0,r1 over this wave's j-half, 2 tiles/iter ----
    {
        const int r0 = rbase + rp * 2;

        float pmEf0[2][8], pmEf1[2][8];
        #pragma unroll
        for (int kt = 0; kt < 2; ++kt) {
            const float4 a0 = *(const float4*)(pm + r0 * C2 + kt * 32 + g * 8);
            const float4 a1 = *(const float4*)(pm + r0 * C2 + kt * 32 + g * 8 + 4);
            pmEf0[kt][0] = EXP2F(a0.x * LOG2E); pmEf0[kt][1] = EXP2F(a0.y * LOG2E);
            pmEf0[kt][2] = EXP2F(a0.z * LOG2E); pmEf0[kt][3] = EXP2F(a0.w * LOG2E);
            pmEf0[kt][4] = EXP2F(a1.x * LOG2E); pmEf0[kt][5] = EXP2F(a1.y * LOG2E);
            pmEf0[kt][6] = EXP2F(a1.z * LOG2E); pmEf0[kt][7] = EXP2F(a1.w * LOG2E);
            const float4 c0 = *(const float4*)(pm + (r0 + 1) * C2 + kt * 32 + g * 8);
            const float4 c1 = *(const float4*)(pm + (r0 + 1) * C2 + kt * 32 + g * 8 + 4);
            pmEf1[kt][0] = EXP2F(c0.x * LOG2E); pmEf1[kt][1] = EXP2F(c0.y * LOG2E);
            pmEf1[kt][2] = EXP2F(c0.z * LOG2E); pmEf1[kt][3] = EXP2F(c0.w * LOG2E);
            pmEf1[kt][4] = EXP2F(c1.x * LOG2E); pmEf1[kt][5] = EXP2F(c1.y * LOG2E);
            pmEf1[kt][6] = EXP2F(c1.z * LOG2E); pmEf1[kt][7] = EXP2F(c1.w * LOG2E);
        }

        half8 ahi[4][2], alo[4][2];      // M rows fp16 hi/lo (2-term, once)
        #pragma unroll
        for (int rt = 0; rt < 4; ++rt) {
            #pragma unroll
            for (int kt = 0; kt < 2; ++kt) {
                const float* mrow = Mf + (rt * 16 + lj) * C2 + kt * 32 + g * 8;
                const float4 m0 = *(const float4*)mrow;
                const float4 m1 = *(const float4*)(mrow + 4);
                float mv[8] = {m0.x, m0.y, m0.z, m0.w, m1.x, m1.y, m1.z, m1.w};
                #pragma unroll
                for (int e = 0; e < 8; ++e) {
                    _Float16 hh = (_Float16)mv[e];          // RNE f32->f16
                    ahi[rt][kt][e] = hh;
                    alo[rt][kt][e] = (_Float16)(mv[e] - (float)hh);
                }
            }
        }

        const int tbase = h * 32;
        const float* p0 = psEb + (long)((tbase + 0) * 16 + lj) * C2 + g * 8;
        const float* p1 = psEb + (long)((tbase + 1) * 16 + lj) * C2 + g * 8;
        float4 cA0 = *(const float4*)(p0);      float4 cA1 = *(const float4*)(p0 + 4);
        float4 cA2 = *(const float4*)(p0 + 32); float4 cA3 = *(const float4*)(p0 + 36);
        float4 cB0 = *(const float4*)(p1);      float4 cB1 = *(const float4*)(p1 + 4);
        float4 cB2 = *(const float4*)(p1 + 32); float4 cB3 = *(const float4*)(p1 + 36);

        #pragma unroll 1
        for (int it = 0; it < 16; ++it) {
            float4 nA0, nA1, nA2, nA3, nB0, nB1, nB2, nB3;
            if (it < 15) {                       // issue next-iter loads EARLY
                const float* q0 = psEb + (long)((tbase + it * 2 + 2) * 16 + lj) * C2 + g * 8;
                const float* q1 = psEb + (long)((tbase + it * 2 + 3) * 16 + lj) * C2 + g * 8;
                nA0 = *(const float4*)(q0);      nA1 = *(const float4*)(q0 + 4);
                nA2 = *(const float4*)(q0 + 32); nA3 = *(const float4*)(q0 + 36);
                nB0 = *(const float4*)(q1);      nB1 = *(const float4*)(q1 + 4);
                nB2 = *(const float4*)(q1 + 32); nB3 = *(const float4*)(q1 + 36);
            }

            f32x4 a0A[4] = {{0,0,0,0},{0,0,0,0},{0,0,0,0},{0,0,0,0}};
            f32x4 a1A[4] = {{0,0,0,0},{0,0,0,0},{0,0,0,0},{0,0,0,0}};
            f32x4 a0B[4] = {{0,0,0,0},{0,0,0,0},{0,0,0,0},{0,0,0,0}};
            f32x4 a1B[4] = {{0,0,0,0},{0,0,0,0},{0,0,0,0},{0,0,0,0}};

            __builtin_amdgcn_s_setprio(1);
            STREAM(pmEf0, cA0, cA1, cA2, cA3, a0A);
            STREAM(pmEf1, cA0, cA1, cA2, cA3, a1A);
            STREAM(pmEf0, cB0, cB1, cB2, cB3, a0B);
            STREAM(pmEf1, cB0, cB1, cB2, cB3, a1B);
            __builtin_amdgcn_s_setprio(0);

            float s0A = 0.f, s1A = 0.f, s0B = 0.f, s1B = 0.f;
            #pragma unroll
            for (int e = 0; e < 4; ++e) {
                s0A = fmaf(a0A[0][e], a0A[0][e], s0A);
                s0A = fmaf(a0A[1][e], a0A[1][e], s0A);
                s0A = fmaf(a0A[2][e], a0A[2][e], s0A);
                s0A = fmaf(a0A[3][e], a0A[3][e], s0A);
                s1A = fmaf(a1A[0][e], a1A[0][e], s1A);
                s1A = fmaf(a1A[1][e], a1A[1][e], s1A);
                s1A = fmaf(a1A[2][e], a1A[2][e], s1A);
                s1A = fmaf(a1A[3][e], a1A[3][e], s1A);
                s0B = fmaf(a0B[0][e], a0B[0][e], s0B);
                s0B = fmaf(a0B[1][e], a0B[1][e], s0B);
                s0B = fmaf(a0B[2][e], a0B[2][e], s0B);
                s0B = fmaf(a0B[3][e], a0B[3][e], s0B);
                s1B = fmaf(a1B[0][e], a1B[0][e], s1B);
                s1B = fmaf(a1B[1][e], a1B[1][e], s1B);
                s1B = fmaf(a1B[2][e], a1B[2][e], s1B);
                s1B = fmaf(a1B[3][e], a1B[3][e], s1B);
            }
            s0A += __shfl_xor(s0A, 16, 64); s0A += __shfl_xor(s0A, 32, 64);
            s1A += __shfl_xor(s1A, 16, 64); s1A += __shfl_xor(s1A, 32, 64);
            s0B += __shfl_xor(s0B, 16, 64); s0B += __shfl_xor(s0B, 32, 64);
            s1B += __shfl_xor(s1B, 16, 64); s1B += __shfl_xor(s1B, 32, 64);
            if (lane < 16) {
                const int jA = (tbase + it * 2 + 0) * 16 + lane;
                const int jB = (tbase + it * 2 + 1) * 16 + lane;
                d2u[rp * 2 + 0][jA] = (__float_as_uint(s0A) & 0xFFFFFC00u) | (uint)jA;
                d2u[rp * 2 + 1][jA] = (__float_as_uint(s1A) & 0xFFFFFC00u) | (uint)jA;
                d2u[rp * 2 + 0][jB] = (__float_as_uint(s0B) & 0xFFFFFC00u) | (uint)jB;
                d2u[rp * 2 + 1][jB] = (__float_as_uint(s1B) & 0xFFFFFC00u) | (uint)jB;
            }

            cA0 = nA0; cA1 = nA1; cA2 = nA2; cA3 = nA3;
            cB0 = nB0; cB1 = nB1; cB2 = nB2; cB3 = nB3;
        }
    }
    __syncthreads();

    // ---- Phases B/C/F: wave wv owns row rbase+wv (R14 path) ----
    const int bi = rbase + wv;
    const int i  = bi & (NN - 1);
    const float pm_own = pm[bi * C2 + lane];

    // Phase B: top-NCAND via packed-uint min passes
    uint v[16];
    #pragma unroll
    for (int q = 0; q < 16; ++q) v[q] = d2u[wv][q * 64 + lane];

    int myCand = 0;
    #pragma unroll 1
    for (int k = 0; k < NCAND; ++k) {
        uint bv = v[0];
        #pragma unroll
        for (int q = 1; q < 16; ++q) bv = min(bv, v[q]);
        #pragma unroll
        for (int st = 0; st < 6; ++st)
            bv = min(bv, (uint)__shfl_xor((int)bv, 1 << st, 64));
        #pragma unroll
        for (int q = 0; q < 16; ++q)
            if (v[q] == bv) v[q] = 0xFFFFFFFFu;
        if (lane == k) myCand = (int)(bv & 0x3FFu);
    }

    // Phase C: np-exact rescore (R6 bit-exact), NCAND candidates,
    // candidate ps loads batched upfront (hide L2 latency).
    float Acol[C2];
    #pragma unroll
    for (int c = 0; c < C2; ++c) Acol[c] = A[c * C2 + lane];

    int jvv[NCAND];
    #pragma unroll
    for (int t = 0; t < NCAND; ++t) jvv[t] = __shfl(myCand, t, 64);
    float pscv[NCAND];
    #pragma unroll
    for (int t = 0; t < NCAND; ++t) pscv[t] = psb[(long)jvv[t] * C2 + lane];

    #pragma unroll 1
    for (int t = 0; t < NCAND; ++t) {
        float e = expf(pscv[t] - pm_own);
        float s_own = 1.0f / __fadd_rn(1.0f, e);     // sigmoid(pm-ps), lane=c
        sC[wv][lane] = s_own;
        LDS_FENCE();
        float wd = 0.f;
        #pragma unroll
        for (int c = 0; c < C2; ++c)                 // ascending c, single acc
            wd = fmaf(sC[wv][c], Acol[c], wd);
        const float t_own = __fmul_rn(wd, s_own);    // t_d = w_d * s_d, lane=d
        // numpy pairwise-8 via shfl (same op order as np)
        float r8 = t_own;
        #pragma unroll
        for (int blk = 1; blk < 8; ++blk)
            r8 = __fadd_rn(r8, __shfl(t_own, (lane & 7) + 8 * blk, 64));
        const float rr0 = __shfl(r8, 0, 64), rr1 = __shfl(r8, 1, 64);
        const float rr2 = __shfl(r8, 2, 64), rr3 = __shfl(r8, 3, 64);
        const float rr4 = __shfl(r8, 4, 64), rr5 = __shfl(r8, 5, 64);
        const float rr6 = __shfl(r8, 6, 64), rr7 = __shfl(r8, 7, 64);
        float dis2 = __fadd_rn(
            __fadd_rn(__fadd_rn(rr0, rr1), __fadd_rn(rr2, rr3)),
            __fadd_rn(__fadd_rn(rr4, rr5), __fadd_rn(rr6, rr7)));
        float disf = sqrtf(dis2);
        float ee = expf(disf);
        float cd = 1.0f / __fadd_rn(1.0f, ee);       // sigmoid(-dis)
        if (lane == 0) cdiffL[wv][t] = cd;
    }
    LDS_FENCE();

    // Final: per-wave top-16 over NCAND exact diffs (desc, index asc)
    float myd = (lane < NCAND) ? cdiffL[wv][lane] : -2.0f;
    int myj = (lane < NCAND) ? myCand : (1 << 20);

    const int obase = b * (NN * KK) + i * KK;        // index chunk (f32)
    const int vbase = 2 * NN * KK + obase;           // value chunk (f32)

    #pragma unroll 1
    for (int k = 0; k < KK; ++k) {
        float bd = myd;
        int bj = myj;
        #pragma unroll
        for (int st = 0; st < 6; ++st) {
            int msk = 1 << st;
            float od = __shfl_xor(bd, msk, 64);
            int oj = __shfl_xor(bj, msk, 64);
            bool better = (od > bd) || (od == bd && oj < bj);
            bd = better ? od : bd;
            bj = better ? oj : bj;
        }
        if (myj == bj) myd = -2.0f;                  // candidate j's unique
        if (lane == 0) {
            out[obase + k] = (float)bj;
            out[vbase + k] = -bd;                    // value = -topk(diff)
        }
    }
}

extern "C" void kernel_launch(void* const* d_in, const int* in_sizes, int n_in,
                              void* d_out, int out_size, void* d_ws, size_t ws_size,
                              hipStream_t stream) {
    const float* X  = (const float*)d_in[0];
    const float* Wm = (const float*)d_in[1];
    const float* Ws = (const float*)d_in[2];
    const float* M  = (const float*)d_in[3];

    float* A   = (float*)d_ws;           // 4096 f   (16 KB)
    float* pm  = A + C2 * C2;            // 131072 f (512 KB)
    float* ps  = pm + 2 * NN * C2;       // 131072 f (512 KB)
    float* psE = ps + 2 * NN * C2;       // 131072 f (512 KB)  total ~1.52 MB
    float* out = (float*)d_out;          // f32: [idx 32768][val 32768]

    hipLaunchKernelGGL(proj_buildA, dim3(2 * NN + 32), dim3(128), 0, stream,
                       X, Wm, Ws, M, pm, ps, psE, A);
    hipLaunchKernelGGL(pair_topk, dim3(512), dim3(256), 0, stream,
                       pm, ps, psE, M, A, out);
}

// Round 20
// 94.582 us; speedup vs baseline: 1.5133x; 1.0452x over previous
//
#include <hip/hip_runtime.h>
#include <hip/hip_bf16.h>
#include <hip/hip_fp16.h>
#include <math.h>

#define NN 1024
#define CC 128
#define C2 64
#define KK 16
#define NCAND 24

#if __has_builtin(__builtin_amdgcn_exp2f)
#define EXP2F(x) __builtin_amdgcn_exp2f(x)
#else
#define EXP2F(x) exp2f(x)
#endif
#define LOG2E 1.4426950408889634f

typedef __fp16  hf2   __attribute__((ext_vector_type(2)));   // cvt_pkrtz result type
typedef _Float16 half8 __attribute__((ext_vector_type(8)));  // MFMA operand type
typedef float f32x4    __attribute__((ext_vector_type(4)));
typedef int   int4v    __attribute__((ext_vector_type(4)));
typedef unsigned int uint;

__device__ __forceinline__ float fast_rcp(float x) {
    return __builtin_amdgcn_rcpf(x);
}

// In-wave LDS write->read visibility: wait LDS ops, pin compiler order.
#define LDS_FENCE() do { \
    asm volatile("s_waitcnt lgkmcnt(0)" ::: "memory"); \
    __builtin_amdgcn_sched_barrier(0); } while (0)

// ---------------- K1: proj (np-exact) + psE, fused with buildA -------------
// blocks [0, 2*NN): proj; blocks [2*NN, 2*NN+32): A = M^T M.
__global__ __launch_bounds__(128) void proj_buildA(
        const float* __restrict__ X,
        const float* __restrict__ Wm,
        const float* __restrict__ Ws,
        const float* __restrict__ M,
        float* __restrict__ pm,
        float* __restrict__ ps,
        float* __restrict__ psE,
        float* __restrict__ A) {
    if (blockIdx.x >= 2 * NN) {          // ---- buildA: 32 blocks x 128 thr
        const int e = (blockIdx.x - 2 * NN) * 128 + threadIdx.x;  // < 4096
        const int c = e >> 6, d = e & 63;
        float acc = 0.f;
        #pragma unroll 8
        for (int r = 0; r < C2; ++r)
            acc = fmaf(M[r * C2 + c], M[r * C2 + d], acc);
        A[e] = acc;                      // A[c][d] row-major
        return;
    }

    const int bn = blockIdx.x;           // b*1024 + n
    const int b  = bn >> 10;
    const int n  = bn & (NN - 1);
    const int t  = threadIdx.x;          // 0..127

    __shared__ float xv[CC];
    xv[t] = X[b * CC * NN + t * NN + n];
    __syncthreads();

    const int d = t & (C2 - 1);
    const float* wr = ((t < C2) ? Wm : Ws) + d * CC;
    float acc = 0.f;
    #pragma unroll
    for (int c = 0; c < CC; ++c)
        acc = fmaf(wr[c], xv[c], acc);   // sequential k-order, single acc

    float a = __fadd_rn(fabsf(acc), 1e-10f);
    float l = logf(a);
    float r = (acc > 0.f) ? l : ((acc < 0.f) ? -l : 0.f);
    if (t < C2) {
        pm[bn * C2 + d] = r;
    } else {
        ps[bn * C2 + d] = r;
        psE[bn * C2 + d] = EXP2F(r * LOG2E);   // e^ps (proxy pass only)
    }
}

// f32 sigmoid -> packed fp16 B-fragment (single term; proxy only).
#define SIGF16(PMEF, Y0, Y1, BF) do {                                         \
    float s0 = PMEF[0] * fast_rcp(PMEF[0] + (Y0).x);                          \
    float s1 = PMEF[1] * fast_rcp(PMEF[1] + (Y0).y);                          \
    float s2 = PMEF[2] * fast_rcp(PMEF[2] + (Y0).z);                          \
    float s3 = PMEF[3] * fast_rcp(PMEF[3] + (Y0).w);                          \
    float s4 = PMEF[4] * fast_rcp(PMEF[4] + (Y1).x);                          \
    float s5 = PMEF[5] * fast_rcp(PMEF[5] + (Y1).y);                          \
    float s6 = PMEF[6] * fast_rcp(PMEF[6] + (Y1).z);                          \
    float s7 = PMEF[7] * fast_rcp(PMEF[7] + (Y1).w);                          \
    hf2 p0 = __builtin_amdgcn_cvt_pkrtz(s0, s1);                              \
    hf2 p1 = __builtin_amdgcn_cvt_pkrtz(s2, s3);                              \
    hf2 p2 = __builtin_amdgcn_cvt_pkrtz(s4, s5);                              \
    hf2 p3 = __builtin_amdgcn_cvt_pkrtz(s6, s7);                              \
    int4v iv = { __builtin_bit_cast(int, p0), __builtin_bit_cast(int, p1),    \
                 __builtin_bit_cast(int, p2), __builtin_bit_cast(int, p3) };  \
    BF = __builtin_bit_cast(half8, iv);                                       \
} while (0)

// SINGLE-term fp16 A (no split): 4 MFMA per kt-fragment.
// fp16(M) RNE error adds ~1.6e-3 to du (~2.5 abs on dis2) vs rank gap ~15.
#define MFMA4(AC, KT, B)                                                              \
    AC[0] = __builtin_amdgcn_mfma_f32_16x16x32_f16(af[0][KT], B, AC[0], 0, 0, 0);     \
    AC[1] = __builtin_amdgcn_mfma_f32_16x16x32_f16(af[1][KT], B, AC[1], 0, 0, 0);     \
    AC[2] = __builtin_amdgcn_mfma_f32_16x16x32_f16(af[2][KT], B, AC[2], 0, 0, 0);     \
    AC[3] = __builtin_amdgcn_mfma_f32_16x16x32_f16(af[3][KT], B, AC[3], 0, 0, 0);

// One stream: build 2 fp16 B-fragments, 8 MFMA
#define STREAM(PMEF, T0, T1, T2, T3, AC) do {                                 \
    half8 b0, b1;                                                             \
    SIGF16(PMEF[0], T0, T1, b0);                                              \
    SIGF16(PMEF[1], T2, T3, b1);                                              \
    MFMA4(AC, 0, b0)                                                          \
    MFMA4(AC, 1, b1)                                                          \
} while (0)

// ---------------- K2: 2 rows x 2 tiles per wave iter, 512 blocks -----------
// Block = 4 waves: wave = (row-pair rp = wv>>1, j-half h = wv&1).
// Phase A: fp16 proxy (A single-term, B single fp16 via cvt_pkrtz).
// Phases B/C/F: wave wv owns row rbase+wv, R14 path (np-exact phase C).
__global__ __launch_bounds__(256, 2) void pair_topk(
        const float* __restrict__ pm,
        const float* __restrict__ ps,
        const float* __restrict__ psE,
        const float* __restrict__ Mf,
        const float* __restrict__ A,
        float* __restrict__ out) {
    const int tid  = threadIdx.x;
    const int wv   = tid >> 6;           // 0..3
    const int lane = tid & 63;
    const int g    = lane >> 4;          // k-group 0..3
    const int lj   = lane & 15;          // col (B) / row (A) within tile
    const int rp   = wv >> 1;            // row-pair 0..1
    const int h    = wv & 1;             // j-half 0..1

    const int rbase = blockIdx.x * 4;    // first row of block (b-uniform)
    const int b     = rbase >> 10;

    __shared__ uint  d2u[4][NN];         // packed (d2 & ~0x3FF) | j  (16 KB)
    __shared__ float sC[4][C2];
    __shared__ float cdiffL[4][NCAND];

    const float* psb  = ps  + b * NN * C2;
    const float* psEb = psE + b * NN * C2;

    // ---- Phase A: rows r0,r1 over this wave's j-half, 2 tiles/iter ----
    {
        const int r0 = rbase + rp * 2;

        float pmEf0[2][8], pmEf1[2][8];
        #pragma unroll
        for (int kt = 0; kt < 2; ++kt) {
            const float4 a0 = *(const float4*)(pm + r0 * C2 + kt * 32 + g * 8);
            const float4 a1 = *(const float4*)(pm + r0 * C2 + kt * 32 + g * 8 + 4);
            pmEf0[kt][0] = EXP2F(a0.x * LOG2E); pmEf0[kt][1] = EXP2F(a0.y * LOG2E);
            pmEf0[kt][2] = EXP2F(a0.z * LOG2E); pmEf0[kt][3] = EXP2F(a0.w * LOG2E);
            pmEf0[kt][4] = EXP2F(a1.x * LOG2E); pmEf0[kt][5] = EXP2F(a1.y * LOG2E);
            pmEf0[kt][6] = EXP2F(a1.z * LOG2E); pmEf0[kt][7] = EXP2F(a1.w * LOG2E);
            const float4 c0 = *(const float4*)(pm + (r0 + 1) * C2 + kt * 32 + g * 8);
            const float4 c1 = *(const float4*)(pm + (r0 + 1) * C2 + kt * 32 + g * 8 + 4);
            pmEf1[kt][0] = EXP2F(c0.x * LOG2E); pmEf1[kt][1] = EXP2F(c0.y * LOG2E);
            pmEf1[kt][2] = EXP2F(c0.z * LOG2E); pmEf1[kt][3] = EXP2F(c0.w * LOG2E);
            pmEf1[kt][4] = EXP2F(c1.x * LOG2E); pmEf1[kt][5] = EXP2F(c1.y * LOG2E);
            pmEf1[kt][6] = EXP2F(c1.z * LOG2E); pmEf1[kt][7] = EXP2F(c1.w * LOG2E);
        }

        half8 af[4][2];                  // M rows single fp16 (RNE, once)
        #pragma unroll
        for (int rt = 0; rt < 4; ++rt) {
            #pragma unroll
            for (int kt = 0; kt < 2; ++kt) {
                const float* mrow = Mf + (rt * 16 + lj) * C2 + kt * 32 + g * 8;
                const float4 m0 = *(const float4*)mrow;
                const float4 m1 = *(const float4*)(mrow + 4);
                float mv[8] = {m0.x, m0.y, m0.z, m0.w, m1.x, m1.y, m1.z, m1.w};
                #pragma unroll
                for (int e = 0; e < 8; ++e)
                    af[rt][kt][e] = (_Float16)mv[e];        // RNE f32->f16
            }
        }

        const int tbase = h * 32;
        const float* p0 = psEb + (long)((tbase + 0) * 16 + lj) * C2 + g * 8;
        const float* p1 = psEb + (long)((tbase + 1) * 16 + lj) * C2 + g * 8;
        float4 cA0 = *(const float4*)(p0);      float4 cA1 = *(const float4*)(p0 + 4);
        float4 cA2 = *(const float4*)(p0 + 32); float4 cA3 = *(const float4*)(p0 + 36);
        float4 cB0 = *(const float4*)(p1);      float4 cB1 = *(const float4*)(p1 + 4);
        float4 cB2 = *(const float4*)(p1 + 32); float4 cB3 = *(const float4*)(p1 + 36);

        #pragma unroll 1
        for (int it = 0; it < 16; ++it) {
            float4 nA0, nA1, nA2, nA3, nB0, nB1, nB2, nB3;
            if (it < 15) {                       // issue next-iter loads EARLY
                const float* q0 = psEb + (long)((tbase + it * 2 + 2) * 16 + lj) * C2 + g * 8;
                const float* q1 = psEb + (long)((tbase + it * 2 + 3) * 16 + lj) * C2 + g * 8;
                nA0 = *(const float4*)(q0);      nA1 = *(const float4*)(q0 + 4);
                nA2 = *(const float4*)(q0 + 32); nA3 = *(const float4*)(q0 + 36);
                nB0 = *(const float4*)(q1);      nB1 = *(const float4*)(q1 + 4);
                nB2 = *(const float4*)(q1 + 32); nB3 = *(const float4*)(q1 + 36);
            }

            f32x4 a0A[4] = {{0,0,0,0},{0,0,0,0},{0,0,0,0},{0,0,0,0}};
            f32x4 a1A[4] = {{0,0,0,0},{0,0,0,0},{0,0,0,0},{0,0,0,0}};
            f32x4 a0B[4] = {{0,0,0,0},{0,0,0,0},{0,0,0,0},{0,0,0,0}};
            f32x4 a1B[4] = {{0,0,0,0},{0,0,0,0},{0,0,0,0},{0,0,0,0}};

            __builtin_amdgcn_s_setprio(1);
            STREAM(pmEf0, cA0, cA1, cA2, cA3, a0A);
            STREAM(pmEf1, cA0, cA1, cA2, cA3, a1A);
            STREAM(pmEf0, cB0, cB1, cB2, cB3, a0B);
            STREAM(pmEf1, cB0, cB1, cB2, cB3, a1B);
            __builtin_amdgcn_s_setprio(0);

            float s0A = 0.f, s1A = 0.f, s0B = 0.f, s1B = 0.f;
            #pragma unroll
            for (int e = 0; e < 4; ++e) {
                s0A = fmaf(a0A[0][e], a0A[0][e], s0A);
                s0A = fmaf(a0A[1][e], a0A[1][e], s0A);
                s0A = fmaf(a0A[2][e], a0A[2][e], s0A);
                s0A = fmaf(a0A[3][e], a0A[3][e], s0A);
                s1A = fmaf(a1A[0][e], a1A[0][e], s1A);
                s1A = fmaf(a1A[1][e], a1A[1][e], s1A);
                s1A = fmaf(a1A[2][e], a1A[2][e], s1A);
                s1A = fmaf(a1A[3][e], a1A[3][e], s1A);
                s0B = fmaf(a0B[0][e], a0B[0][e], s0B);
                s0B = fmaf(a0B[1][e], a0B[1][e], s0B);
                s0B = fmaf(a0B[2][e], a0B[2][e], s0B);
                s0B = fmaf(a0B[3][e], a0B[3][e], s0B);
                s1B = fmaf(a1B[0][e], a1B[0][e], s1B);
                s1B = fmaf(a1B[1][e], a1B[1][e], s1B);
                s1B = fmaf(a1B[2][e], a1B[2][e], s1B);
                s1B = fmaf(a1B[3][e], a1B[3][e], s1B);
            }
            s0A += __shfl_xor(s0A, 16, 64); s0A += __shfl_xor(s0A, 32, 64);
            s1A += __shfl_xor(s1A, 16, 64); s1A += __shfl_xor(s1A, 32, 64);
            s0B += __shfl_xor(s0B, 16, 64); s0B += __shfl_xor(s0B, 32, 64);
            s1B += __shfl_xor(s1B, 16, 64); s1B += __shfl_xor(s1B, 32, 64);
            if (lane < 16) {
                const int jA = (tbase + it * 2 + 0) * 16 + lane;
                const int jB = (tbase + it * 2 + 1) * 16 + lane;
                d2u[rp * 2 + 0][jA] = (__float_as_uint(s0A) & 0xFFFFFC00u) | (uint)jA;
                d2u[rp * 2 + 1][jA] = (__float_as_uint(s1A) & 0xFFFFFC00u) | (uint)jA;
                d2u[rp * 2 + 0][jB] = (__float_as_uint(s0B) & 0xFFFFFC00u) | (uint)jB;
                d2u[rp * 2 + 1][jB] = (__float_as_uint(s1B) & 0xFFFFFC00u) | (uint)jB;
            }

            cA0 = nA0; cA1 = nA1; cA2 = nA2; cA3 = nA3;
            cB0 = nB0; cB1 = nB1; cB2 = nB2; cB3 = nB3;
        }
    }
    __syncthreads();

    // ---- Phases B/C/F: wave wv owns row rbase+wv (R14 path) ----
    const int bi = rbase + wv;
    const int i  = bi & (NN - 1);
    const float pm_own = pm[bi * C2 + lane];

    // Phase B: top-NCAND via packed-uint min passes
    uint v[16];
    #pragma unroll
    for (int q = 0; q < 16; ++q) v[q] = d2u[wv][q * 64 + lane];

    int myCand = 0;
    #pragma unroll 1
    for (int k = 0; k < NCAND; ++k) {
        uint bv = v[0];
        #pragma unroll
        for (int q = 1; q < 16; ++q) bv = min(bv, v[q]);
        #pragma unroll
        for (int st = 0; st < 6; ++st)
            bv = min(bv, (uint)__shfl_xor((int)bv, 1 << st, 64));
        #pragma unroll
        for (int q = 0; q < 16; ++q)
            if (v[q] == bv) v[q] = 0xFFFFFFFFu;
        if (lane == k) myCand = (int)(bv & 0x3FFu);
    }

    // Phase C: np-exact rescore (R6 bit-exact), NCAND candidates,
    // candidate ps loads batched upfront (hide L2 latency).
    float Acol[C2];
    #pragma unroll
    for (int c = 0; c < C2; ++c) Acol[c] = A[c * C2 + lane];

    int jvv[NCAND];
    #pragma unroll
    for (int t = 0; t < NCAND; ++t) jvv[t] = __shfl(myCand, t, 64);
    float pscv[NCAND];
    #pragma unroll
    for (int t = 0; t < NCAND; ++t) pscv[t] = psb[(long)jvv[t] * C2 + lane];

    #pragma unroll 1
    for (int t = 0; t < NCAND; ++t) {
        float e = expf(pscv[t] - pm_own);
        float s_own = 1.0f / __fadd_rn(1.0f, e);     // sigmoid(pm-ps), lane=c
        sC[wv][lane] = s_own;
        LDS_FENCE();
        float wd = 0.f;
        #pragma unroll
        for (int c = 0; c < C2; ++c)                 // ascending c, single acc
            wd = fmaf(sC[wv][c], Acol[c], wd);
        const float t_own = __fmul_rn(wd, s_own);    // t_d = w_d * s_d, lane=d
        // numpy pairwise-8 via shfl (same op order as np)
        float r8 = t_own;
        #pragma unroll
        for (int blk = 1; blk < 8; ++blk)
            r8 = __fadd_rn(r8, __shfl(t_own, (lane & 7) + 8 * blk, 64));
        const float rr0 = __shfl(r8, 0, 64), rr1 = __shfl(r8, 1, 64);
        const float rr2 = __shfl(r8, 2, 64), rr3 = __shfl(r8, 3, 64);
        const float rr4 = __shfl(r8, 4, 64), rr5 = __shfl(r8, 5, 64);
        const float rr6 = __shfl(r8, 6, 64), rr7 = __shfl(r8, 7, 64);
        float dis2 = __fadd_rn(
            __fadd_rn(__fadd_rn(rr0, rr1), __fadd_rn(rr2, rr3)),
            __fadd_rn(__fadd_rn(rr4, rr5), __fadd_rn(rr6, rr7)));
        float disf = sqrtf(dis2);
        float ee = expf(disf);
        float cd = 1.0f / __fadd_rn(1.0f, ee);       // sigmoid(-dis)
        if (lane == 0) cdiffL[wv][t] = cd;
    }
    LDS_FENCE();

    // Final: per-wave top-16 over NCAND exact diffs (desc, index asc)
    float myd = (lane < NCAND) ? cdiffL[wv][lane] : -2.0f;
    int myj = (lane < NCAND) ? myCand : (1 << 20);

    const int obase = b * (NN * KK) + i * KK;        // index chunk (f32)
    const int vbase = 2 * NN * KK + obase;           // value chunk (f32)

    #pragma unroll 1
    for (int k = 0; k < KK; ++k) {
        float bd = myd;
        int bj = myj;
        #pragma unroll
        for (int st = 0; st < 6; ++st) {
            int msk = 1 << st;
            float od = __shfl_xor(bd, msk, 64);
            int oj = __shfl_xor(bj, msk, 64);
            bool better = (od > bd) || (od == bd && oj < bj);
            bd = better ? od : bd;
            bj = better ? oj : bj;
        }
        if (myj == bj) myd = -2.0f;                  // candidate j's unique
        if (lane == 0) {
            out[obase + k] = (float)bj;
            out[vbase + k] = -bd;                    // value = -topk(diff)
        }
    }
}

extern "C" void kernel_launch(void* const* d_in, const int* in_sizes, int n_in,
                              void* d_out, int out_size, void* d_ws, size_t ws_size,
                              hipStream_t stream) {
    const float* X  = (const float*)d_in[0];
    const float* Wm = (const float*)d_in[1];
    const float* Ws = (const float*)d_in[2];
    const float* M  = (const float*)d_in[3];

    float* A   = (float*)d_ws;           // 4096 f   (16 KB)
    float* pm  = A + C2 * C2;            // 131072 f (512 KB)
    float* ps  = pm + 2 * NN * C2;       // 131072 f (512 KB)
    float* psE = ps + 2 * NN * C2;       // 131072 f (512 KB)  total ~1.52 MB
    float* out = (float*)d_out;          // f32: [idx 32768][val 32768]

    hipLaunchKernelGGL(proj_buildA, dim3(2 * NN + 32), dim3(128), 0, stream,
                       X, Wm, Ws, M, pm, ps, psE, A);
    hipLaunchKernelGGL(pair_topk, dim3(512), dim3(256), 0, stream,
                       pm, ps, psE, M, A, out);
}

// Round 21
// 88.566 us; speedup vs baseline: 1.6161x; 1.0679x over previous
//
#include <hip/hip_runtime.h>
#include <hip/hip_bf16.h>
#include <hip/hip_fp16.h>
#include <math.h>

#define NN 1024
#define CC 128
#define C2 64
#define KK 16
#define NCAND 24

#if __has_builtin(__builtin_amdgcn_exp2f)
#define EXP2F(x) __builtin_amdgcn_exp2f(x)
#else
#define EXP2F(x) exp2f(x)
#endif
#define LOG2E 1.4426950408889634f

typedef __fp16  hf2   __attribute__((ext_vector_type(2)));   // cvt_pkrtz result type
typedef _Float16 half8 __attribute__((ext_vector_type(8)));  // MFMA operand type
typedef float f32x4    __attribute__((ext_vector_type(4)));
typedef int   int4v    __attribute__((ext_vector_type(4)));
typedef unsigned int uint;

__device__ __forceinline__ float fast_rcp(float x) {
    return __builtin_amdgcn_rcpf(x);
}

// In-wave LDS write->read visibility: wait LDS ops, pin compiler order.
#define LDS_FENCE() do { \
    asm volatile("s_waitcnt lgkmcnt(0)" ::: "memory"); \
    __builtin_amdgcn_sched_barrier(0); } while (0)

// ---------------- K1: proj (np-exact) + psE, fused with buildA -------------
// blocks [0, 2*NN): proj; blocks [2*NN, 2*NN+32): A = M^T M.
__global__ __launch_bounds__(128) void proj_buildA(
        const float* __restrict__ X,
        const float* __restrict__ Wm,
        const float* __restrict__ Ws,
        const float* __restrict__ M,
        float* __restrict__ pm,
        float* __restrict__ ps,
        float* __restrict__ psE,
        float* __restrict__ A) {
    if (blockIdx.x >= 2 * NN) {          // ---- buildA: 32 blocks x 128 thr
        const int e = (blockIdx.x - 2 * NN) * 128 + threadIdx.x;  // < 4096
        const int c = e >> 6, d = e & 63;
        float acc = 0.f;
        #pragma unroll 8
        for (int r = 0; r < C2; ++r)
            acc = fmaf(M[r * C2 + c], M[r * C2 + d], acc);
        A[e] = acc;                      // A[c][d] row-major
        return;
    }

    const int bn = blockIdx.x;           // b*1024 + n
    const int b  = bn >> 10;
    const int n  = bn & (NN - 1);
    const int t  = threadIdx.x;          // 0..127

    __shared__ float xv[CC];
    xv[t] = X[b * CC * NN + t * NN + n];
    __syncthreads();

    const int d = t & (C2 - 1);
    const float* wr = ((t < C2) ? Wm : Ws) + d * CC;
    float acc = 0.f;
    #pragma unroll
    for (int c = 0; c < CC; ++c)
        acc = fmaf(wr[c], xv[c], acc);   // sequential k-order, single acc

    float a = __fadd_rn(fabsf(acc), 1e-10f);
    float l = logf(a);
    float r = (acc > 0.f) ? l : ((acc < 0.f) ? -l : 0.f);
    if (t < C2) {
        pm[bn * C2 + d] = r;
    } else {
        ps[bn * C2 + d] = r;
        psE[bn * C2 + d] = EXP2F(r * LOG2E);   // e^ps (proxy pass only)
    }
}

// f32 sigmoid -> packed fp16 B-fragment (single term; proxy only).
#define SIGF16(PMEF, Y0, Y1, BF) do {                                         \
    float s0 = PMEF[0] * fast_rcp(PMEF[0] + (Y0).x);                          \
    float s1 = PMEF[1] * fast_rcp(PMEF[1] + (Y0).y);                          \
    float s2 = PMEF[2] * fast_rcp(PMEF[2] + (Y0).z);                          \
    float s3 = PMEF[3] * fast_rcp(PMEF[3] + (Y0).w);                          \
    float s4 = PMEF[4] * fast_rcp(PMEF[4] + (Y1).x);                          \
    float s5 = PMEF[5] * fast_rcp(PMEF[5] + (Y1).y);                          \
    float s6 = PMEF[6] * fast_rcp(PMEF[6] + (Y1).z);                          \
    float s7 = PMEF[7] * fast_rcp(PMEF[7] + (Y1).w);                          \
    hf2 p0 = __builtin_amdgcn_cvt_pkrtz(s0, s1);                              \
    hf2 p1 = __builtin_amdgcn_cvt_pkrtz(s2, s3);                              \
    hf2 p2 = __builtin_amdgcn_cvt_pkrtz(s4, s5);                              \
    hf2 p3 = __builtin_amdgcn_cvt_pkrtz(s6, s7);                              \
    int4v iv = { __builtin_bit_cast(int, p0), __builtin_bit_cast(int, p1),    \
                 __builtin_bit_cast(int, p2), __builtin_bit_cast(int, p3) };  \
    BF = __builtin_bit_cast(half8, iv);                                       \
} while (0)

// SINGLE-term fp16 A: 4 MFMA per kt-fragment.
#define MFMA4(AC, KT, B)                                                              \
    AC[0] = __builtin_amdgcn_mfma_f32_16x16x32_f16(af[0][KT], B, AC[0], 0, 0, 0);     \
    AC[1] = __builtin_amdgcn_mfma_f32_16x16x32_f16(af[1][KT], B, AC[1], 0, 0, 0);     \
    AC[2] = __builtin_amdgcn_mfma_f32_16x16x32_f16(af[2][KT], B, AC[2], 0, 0, 0);     \
    AC[3] = __builtin_amdgcn_mfma_f32_16x16x32_f16(af[3][KT], B, AC[3], 0, 0, 0);

// One stream: build 2 fp16 B-fragments, 8 MFMA
#define STREAM(PMEF, T0, T1, T2, T3, AC) do {                                 \
    half8 b0, b1;                                                             \
    SIGF16(PMEF[0], T0, T1, b0);                                              \
    SIGF16(PMEF[1], T2, T3, b1);                                              \
    MFMA4(AC, 0, b0)                                                          \
    MFMA4(AC, 1, b1)                                                          \
} while (0)

#define SQUARE16(AC, S) do {                                                  \
    _Pragma("unroll")                                                         \
    for (int e = 0; e < 4; ++e) {                                             \
        S = fmaf(AC[0][e], AC[0][e], S);                                      \
        S = fmaf(AC[1][e], AC[1][e], S);                                      \
        S = fmaf(AC[2][e], AC[2][e], S);                                      \
        S = fmaf(AC[3][e], AC[3][e], S);                                      \
    }                                                                         \
} while (0)

// ---------------- K2: 4 rows per wave x quarter-j, 512 blocks --------------
// Block = 4 waves = 4 rows. Wave wv covers j-tiles [wv*16, wv*16+16) for ALL
// 4 block rows: ONE psE tile load feeds 4 rows' sigmoid+MFMA streams (psE
// read once per block, 4x compute per load). d2u[r][j]: wave writes its
// quarter for each local row r. Barrier. Phases B/C/F: wave wv owns local
// row wv (np-exact phase C, 2-candidate interleaved for latency).
__global__ __launch_bounds__(256, 2) void pair_topk(
        const float* __restrict__ pm,
        const float* __restrict__ ps,
        const float* __restrict__ psE,
        const float* __restrict__ Mf,
        const float* __restrict__ A,
        float* __restrict__ out) {
    const int tid  = threadIdx.x;
    const int wv   = tid >> 6;           // 0..3 (j-quarter in phase A; row in B/C/F)
    const int lane = tid & 63;
    const int g    = lane >> 4;          // k-group 0..3
    const int lj   = lane & 15;          // col (B) / row (A) within tile

    const int rbase = blockIdx.x * 4;    // first row of block (b-uniform)
    const int b     = rbase >> 10;

    __shared__ uint  d2u[4][NN];         // packed (d2 & ~0x3FF) | j  (16 KB)
    __shared__ float sC[4][2][C2];
    __shared__ float cdiffL[4][NCAND];

    const float* psb  = ps  + b * NN * C2;
    const float* psEb = psE + b * NN * C2;

    // ---- Phase A: 4 rows over this wave's j-quarter, 1 tile/iter ----
    {
        float pmEf[4][2][8];             // e^pm fragments, all 4 block rows
        #pragma unroll
        for (int r = 0; r < 4; ++r) {
            #pragma unroll
            for (int kt = 0; kt < 2; ++kt) {
                const float4 a0 = *(const float4*)(pm + (rbase + r) * C2 + kt * 32 + g * 8);
                const float4 a1 = *(const float4*)(pm + (rbase + r) * C2 + kt * 32 + g * 8 + 4);
                pmEf[r][kt][0] = EXP2F(a0.x * LOG2E); pmEf[r][kt][1] = EXP2F(a0.y * LOG2E);
                pmEf[r][kt][2] = EXP2F(a0.z * LOG2E); pmEf[r][kt][3] = EXP2F(a0.w * LOG2E);
                pmEf[r][kt][4] = EXP2F(a1.x * LOG2E); pmEf[r][kt][5] = EXP2F(a1.y * LOG2E);
                pmEf[r][kt][6] = EXP2F(a1.z * LOG2E); pmEf[r][kt][7] = EXP2F(a1.w * LOG2E);
            }
        }

        half8 af[4][2];                  // M rows single fp16 (RNE, once)
        #pragma unroll
        for (int rt = 0; rt < 4; ++rt) {
            #pragma unroll
            for (int kt = 0; kt < 2; ++kt) {
                const float* mrow = Mf + (rt * 16 + lj) * C2 + kt * 32 + g * 8;
                const float4 m0 = *(const float4*)mrow;
                const float4 m1 = *(const float4*)(mrow + 4);
                float mv[8] = {m0.x, m0.y, m0.z, m0.w, m1.x, m1.y, m1.z, m1.w};
                #pragma unroll
                for (int e = 0; e < 8; ++e)
                    af[rt][kt][e] = (_Float16)mv[e];        // RNE f32->f16
            }
        }

        const int tbase = wv * 16;       // this wave's 16 tiles
        const float* p0 = psEb + (long)((tbase + 0) * 16 + lj) * C2 + g * 8;
        float4 c0 = *(const float4*)(p0);      float4 c1 = *(const float4*)(p0 + 4);
        float4 c2 = *(const float4*)(p0 + 32); float4 c3 = *(const float4*)(p0 + 36);

        #pragma unroll 1
        for (int it = 0; it < 16; ++it) {
            float4 n0, n1, n2, n3;
            if (it < 15) {                       // issue next-tile loads EARLY
                const float* q0 = psEb + (long)((tbase + it + 1) * 16 + lj) * C2 + g * 8;
                n0 = *(const float4*)(q0);      n1 = *(const float4*)(q0 + 4);
                n2 = *(const float4*)(q0 + 32); n3 = *(const float4*)(q0 + 36);
            }

            f32x4 ac0[4] = {{0,0,0,0},{0,0,0,0},{0,0,0,0},{0,0,0,0}};
            f32x4 ac1[4] = {{0,0,0,0},{0,0,0,0},{0,0,0,0},{0,0,0,0}};
            f32x4 ac2[4] = {{0,0,0,0},{0,0,0,0},{0,0,0,0},{0,0,0,0}};
            f32x4 ac3[4] = {{0,0,0,0},{0,0,0,0},{0,0,0,0},{0,0,0,0}};

            __builtin_amdgcn_s_setprio(1);
            STREAM(pmEf[0], c0, c1, c2, c3, ac0);
            STREAM(pmEf[1], c0, c1, c2, c3, ac1);
            STREAM(pmEf[2], c0, c1, c2, c3, ac2);
            STREAM(pmEf[3], c0, c1, c2, c3, ac3);
            __builtin_amdgcn_s_setprio(0);

            float s0 = 0.f, s1 = 0.f, s2 = 0.f, s3 = 0.f;
            SQUARE16(ac0, s0);
            SQUARE16(ac1, s1);
            SQUARE16(ac2, s2);
            SQUARE16(ac3, s3);
            s0 += __shfl_xor(s0, 16, 64); s0 += __shfl_xor(s0, 32, 64);
            s1 += __shfl_xor(s1, 16, 64); s1 += __shfl_xor(s1, 32, 64);
            s2 += __shfl_xor(s2, 16, 64); s2 += __shfl_xor(s2, 32, 64);
            s3 += __shfl_xor(s3, 16, 64); s3 += __shfl_xor(s3, 32, 64);
            if (lane < 16) {
                const int jj = (tbase + it) * 16 + lane;
                d2u[0][jj] = (__float_as_uint(s0) & 0xFFFFFC00u) | (uint)jj;
                d2u[1][jj] = (__float_as_uint(s1) & 0xFFFFFC00u) | (uint)jj;
                d2u[2][jj] = (__float_as_uint(s2) & 0xFFFFFC00u) | (uint)jj;
                d2u[3][jj] = (__float_as_uint(s3) & 0xFFFFFC00u) | (uint)jj;
            }

            c0 = n0; c1 = n1; c2 = n2; c3 = n3;
        }
    }
    __syncthreads();

    // ---- Phases B/C/F: wave wv owns row rbase+wv ----
    const int bi = rbase + wv;
    const int i  = bi & (NN - 1);
    const float pm_own = pm[bi * C2 + lane];

    // Phase B: top-NCAND via packed-uint min passes
    uint v[16];
    #pragma unroll
    for (int q = 0; q < 16; ++q) v[q] = d2u[wv][q * 64 + lane];

    int myCand = 0;
    #pragma unroll 1
    for (int k = 0; k < NCAND; ++k) {
        uint bv = v[0];
        #pragma unroll
        for (int q = 1; q < 16; ++q) bv = min(bv, v[q]);
        #pragma unroll
        for (int st = 0; st < 6; ++st)
            bv = min(bv, (uint)__shfl_xor((int)bv, 1 << st, 64));
        #pragma unroll
        for (int q = 0; q < 16; ++q)
            if (v[q] == bv) v[q] = 0xFFFFFFFFu;
        if (lane == k) myCand = (int)(bv & 0x3FFu);
    }

    // Phase C: np-exact rescore (R6 bit-exact op order per candidate),
    // TWO candidates in flight (independent serial chains -> 2x latency hide)
    float Acol[C2];
    #pragma unroll
    for (int c = 0; c < C2; ++c) Acol[c] = A[c * C2 + lane];

    int jvv[NCAND];
    #pragma unroll
    for (int t = 0; t < NCAND; ++t) jvv[t] = __shfl(myCand, t, 64);
    float pscv[NCAND];
    #pragma unroll
    for (int t = 0; t < NCAND; ++t) pscv[t] = psb[(long)jvv[t] * C2 + lane];

    #pragma unroll 1
    for (int t = 0; t < NCAND; t += 2) {
        float e0 = expf(pscv[t]     - pm_own);
        float e1 = expf(pscv[t + 1] - pm_own);
        float sA = 1.0f / __fadd_rn(1.0f, e0);       // sigmoid(pm-ps), lane=c
        float sB = 1.0f / __fadd_rn(1.0f, e1);
        sC[wv][0][lane] = sA;
        sC[wv][1][lane] = sB;
        LDS_FENCE();
        float wd0 = 0.f, wd1 = 0.f;
        #pragma unroll
        for (int c = 0; c < C2; ++c) {               // ascending c, single acc each
            wd0 = fmaf(sC[wv][0][c], Acol[c], wd0);
            wd1 = fmaf(sC[wv][1][c], Acol[c], wd1);
        }
        const float t0 = __fmul_rn(wd0, sA);         // t_d = w_d * s_d, lane=d
        const float t1 = __fmul_rn(wd1, sB);
        // numpy pairwise-8 via shfl (same op order as np), both candidates
        float r80 = t0, r81 = t1;
        #pragma unroll
        for (int blk = 1; blk < 8; ++blk) {
            r80 = __fadd_rn(r80, __shfl(t0, (lane & 7) + 8 * blk, 64));
            r81 = __fadd_rn(r81, __shfl(t1, (lane & 7) + 8 * blk, 64));
        }
        float dis2a = __fadd_rn(
            __fadd_rn(__fadd_rn(__shfl(r80, 0, 64), __shfl(r80, 1, 64)),
                      __fadd_rn(__shfl(r80, 2, 64), __shfl(r80, 3, 64))),
            __fadd_rn(__fadd_rn(__shfl(r80, 4, 64), __shfl(r80, 5, 64)),
                      __fadd_rn(__shfl(r80, 6, 64), __shfl(r80, 7, 64))));
        float dis2b = __fadd_rn(
            __fadd_rn(__fadd_rn(__shfl(r81, 0, 64), __shfl(r81, 1, 64)),
                      __fadd_rn(__shfl(r81, 2, 64), __shfl(r81, 3, 64))),
            __fadd_rn(__fadd_rn(__shfl(r81, 4, 64), __shfl(r81, 5, 64)),
                      __fadd_rn(__shfl(r81, 6, 64), __shfl(r81, 7, 64))));
        float cda = 1.0f / __fadd_rn(1.0f, expf(sqrtf(dis2a)));  // sigmoid(-dis)
        float cdb = 1.0f / __fadd_rn(1.0f, expf(sqrtf(dis2b)));
        if (lane == 0) {
            cdiffL[wv][t]     = cda;
            cdiffL[wv][t + 1] = cdb;
        }
    }
    LDS_FENCE();

    // Final: per-wave top-16 over NCAND exact diffs (desc, index asc)
    float myd = (lane < NCAND) ? cdiffL[wv][lane] : -2.0f;
    int myj = (lane < NCAND) ? myCand : (1 << 20);

    const int obase = b * (NN * KK) + i * KK;        // index chunk (f32)
    const int vbase = 2 * NN * KK + obase;           // value chunk (f32)

    #pragma unroll 1
    for (int k = 0; k < KK; ++k) {
        float bd = myd;
        int bj = myj;
        #pragma unroll
        for (int st = 0; st < 6; ++st) {
            int msk = 1 << st;
            float od = __shfl_xor(bd, msk, 64);
            int oj = __shfl_xor(bj, msk, 64);
            bool better = (od > bd) || (od == bd && oj < bj);
            bd = better ? od : bd;
            bj = better ? oj : bj;
        }
        if (myj == bj) myd = -2.0f;                  // candidate j's unique
        if (lane == 0) {
            out[obase + k] = (float)bj;
            out[vbase + k] = -bd;                    // value = -topk(diff)
        }
    }
}

extern "C" void kernel_launch(void* const* d_in, const int* in_sizes, int n_in,
                              void* d_out, int out_size, void* d_ws, size_t ws_size,
                              hipStream_t stream) {
    const float* X  = (const float*)d_in[0];
    const float* Wm = (const float*)d_in[1];
    const float* Ws = (const float*)d_in[2];
    const float* M  = (const float*)d_in[3];

    float* A   = (float*)d_ws;           // 4096 f   (16 KB)
    float* pm  = A + C2 * C2;            // 131072 f (512 KB)
    float* ps  = pm + 2 * NN * C2;       // 131072 f (512 KB)
    float* psE = ps + 2 * NN * C2;       // 131072 f (512 KB)  total ~1.52 MB
    float* out = (float*)d_out;          // f32: [idx 32768][val 32768]

    hipLaunchKernelGGL(proj_buildA, dim3(2 * NN + 32), dim3(128), 0, stream,
                       X, Wm, Ws, M, pm, ps, psE, A);
    hipLaunchKernelGGL(pair_topk, dim3(512), dim3(256), 0, stream,
                       pm, ps, psE, M, A, out);
}